// Round 8
// baseline (1227.407 us; speedup 1.0000x reference)
//
#include <hip/hip_runtime.h>

typedef float f32x4 __attribute__((ext_vector_type(4)));
typedef short short8 __attribute__((ext_vector_type(8)));

#define T_LEN 2048
#define HD 256
#define SD 64
#define DIN 768
#define DOUT 768
#define NCHUNK 64
#define CLEN 32
#define SCAN_BLKS 512

__device__ __forceinline__ unsigned short f2bf(float f) {
    unsigned int u = __float_as_uint(f);
    unsigned int r = u + 0x7FFFu + ((u >> 16) & 1u);
    return (unsigned short)(r >> 16);
}
__device__ __forceinline__ float bf2f(unsigned short h) {
    return __uint_as_float(((unsigned int)h) << 16);
}
__device__ __forceinline__ int swz(int row, int col, int stride) {
    return row * stride + (col ^ ((row & 7) << 3));
}

// ---------------- manual grid barrier (co-resident grid; launch_bounds-guaranteed) ----------------
__device__ __forceinline__ void gbar(int* cnt, int* gen, int nblk) {
    __syncthreads();
    if (threadIdx.x == 0) {
        __threadfence();
        int g = __hip_atomic_load(gen, __ATOMIC_RELAXED, __HIP_MEMORY_SCOPE_AGENT);
        int v = __hip_atomic_fetch_add(cnt, 1, __ATOMIC_ACQ_REL, __HIP_MEMORY_SCOPE_AGENT);
        if (v == nblk - 1) {
            __hip_atomic_store(cnt, 0, __ATOMIC_RELAXED, __HIP_MEMORY_SCOPE_AGENT);
            __hip_atomic_fetch_add(gen, 1, __ATOMIC_ACQ_REL, __HIP_MEMORY_SCOPE_AGENT);
        } else {
            while (__hip_atomic_load(gen, __ATOMIC_ACQUIRE, __HIP_MEMORY_SCOPE_AGENT) == g) {}
        }
        __threadfence();
    }
    __syncthreads();
}

// ---------------- weight conversion ----------------
__global__ __launch_bounds__(256) void cvt_w_k(const float* __restrict__ s0, const float* __restrict__ s1,
                                               const float* __restrict__ s2, const float* __restrict__ s3,
                                               const float* __restrict__ s4, const float* __restrict__ s5,
                                               unsigned short* __restrict__ d) {
    int i = blockIdx.x * 256 + threadIdx.x;
    if (i >= 1048576) return;
    float v;
    if (i < 196608)      v = s0[i];
    else if (i < 262144) v = s1[i - 196608];
    else if (i < 524288) v = s2[i - 262144];
    else if (i < 786432) v = s3[i - 524288];
    else if (i < 851968) v = s4[i - 786432];
    else                 v = s5[i - 851968];
    d[i] = f2bf(v);
}

// ---------------- A^32 via bf16-split MFMA (5 squarings) ----------------
__global__ __launch_bounds__(256) void matpow_k(const float* __restrict__ A, float* __restrict__ Apow) {
    __shared__ unsigned short Mh[4096], Ml[4096], MhT[4096], MlT[4096];
    const int l = blockIdx.x, tid = threadIdx.x;
    const int w = tid >> 6, ln = tid & 63, ll = ln & 15, lh = ln >> 4;
    const float* src = A + l * 4096;
    for (int i = tid; i < 4096; i += 256) {
        float v = src[i];
        unsigned short hi = f2bf(v);
        unsigned short lo = f2bf(v - bf2f(hi));
        int r = i >> 6, c = i & 63;
        Mh[swz(r, c, 64)] = hi;  Ml[swz(r, c, 64)] = lo;
        MhT[swz(c, r, 64)] = hi; MlT[swz(c, r, 64)] = lo;
    }
    __syncthreads();
    for (int it = 0; it < 5; it++) {   // A^(2^5) = A^32
        f32x4 acc[4] = {};
#pragma unroll
        for (int ks = 0; ks < 2; ks++) {
            int ar = w * 16 + ll, c0 = ks * 32 + lh * 8;
            short8 ah = *reinterpret_cast<const short8*>(&Mh[swz(ar, c0, 64)]);
            short8 al = *reinterpret_cast<const short8*>(&Ml[swz(ar, c0, 64)]);
#pragma unroll
            for (int nf = 0; nf < 4; nf++) {
                int br = nf * 16 + ll;
                short8 bh = *reinterpret_cast<const short8*>(&MhT[swz(br, c0, 64)]);
                short8 bl = *reinterpret_cast<const short8*>(&MlT[swz(br, c0, 64)]);
                acc[nf] = __builtin_amdgcn_mfma_f32_16x16x32_bf16(ah, bh, acc[nf], 0, 0, 0);
                acc[nf] = __builtin_amdgcn_mfma_f32_16x16x32_bf16(ah, bl, acc[nf], 0, 0, 0);
                acc[nf] = __builtin_amdgcn_mfma_f32_16x16x32_bf16(al, bh, acc[nf], 0, 0, 0);
            }
        }
        __syncthreads();
#pragma unroll
        for (int nf = 0; nf < 4; nf++)
#pragma unroll
            for (int r = 0; r < 4; r++) {
                float v = acc[nf][r];
                int row = w * 16 + lh * 4 + r, col = nf * 16 + ll;
                unsigned short hi = f2bf(v);
                unsigned short lo = f2bf(v - bf2f(hi));
                Mh[swz(row, col, 64)] = hi;  Ml[swz(row, col, 64)] = lo;
                MhT[swz(col, row, 64)] = hi; MlT[swz(col, row, 64)] = lo;
            }
        __syncthreads();
    }
    for (int i = tid; i < 4096; i += 256) {
        int r = i >> 6, c = i & 63;
        Apow[l * 4096 + i] = bf2f(Mh[swz(r, c, 64)]) + bf2f(Ml[swz(r, c, 64)]);
    }
}

// ---------------- fused in-proj (fp32 x direct) + LN, BM=32, full N=256 ----------------
__global__ __launch_bounds__(256) void in_ln_k(const float* __restrict__ x,
                                               const unsigned short* __restrict__ w_in,
                                               const float* __restrict__ inb,
                                               const float* __restrict__ lng, const float* __restrict__ lnb,
                                               float* __restrict__ h, unsigned short* __restrict__ xnb) {
    __shared__ float hnf[32 * 260];
    const int tid = threadIdx.x, l = tid & 63, w = tid >> 6;
    const int ll = l & 15, lh = l >> 4;
    const int mf = w >> 1, nh = w & 1;
    const int m0 = blockIdx.x * 32;
    const float* Ap = x + (size_t)(m0 + mf * 16 + ll) * DIN + lh * 8;
    const unsigned short* Wp = w_in + (size_t)(nh * 128 + ll) * DIN + lh * 8;
    f32x4 acc[8] = {};
#pragma unroll
    for (int kb = 0; kb < DIN; kb += 128) {
        short8 af[4];
#pragma unroll
        for (int ks = 0; ks < 4; ks++) {
            float4 a0 = *reinterpret_cast<const float4*>(Ap + kb + ks * 32);
            float4 a1 = *reinterpret_cast<const float4*>(Ap + kb + ks * 32 + 4);
            short8 t;
            t[0] = (short)f2bf(a0.x); t[1] = (short)f2bf(a0.y);
            t[2] = (short)f2bf(a0.z); t[3] = (short)f2bf(a0.w);
            t[4] = (short)f2bf(a1.x); t[5] = (short)f2bf(a1.y);
            t[6] = (short)f2bf(a1.z); t[7] = (short)f2bf(a1.w);
            af[ks] = t;
        }
#pragma unroll
        for (int half = 0; half < 2; half++) {
            short8 bfx[8][2];
#pragma unroll
            for (int ks = 0; ks < 2; ks++)
#pragma unroll
                for (int j = 0; j < 8; j++)
                    bfx[j][ks] = *reinterpret_cast<const short8*>(Wp + (size_t)(j * 16) * DIN + kb + (half * 2 + ks) * 32);
#pragma unroll
            for (int ks = 0; ks < 2; ks++)
#pragma unroll
                for (int j = 0; j < 8; j++)
                    acc[j] = __builtin_amdgcn_mfma_f32_16x16x32_bf16(af[half * 2 + ks], bfx[j][ks], acc[j], 0, 0, 0);
        }
    }
#pragma unroll
    for (int j = 0; j < 8; j++)
#pragma unroll
        for (int r = 0; r < 4; r++) {
            int rowl = mf * 16 + lh * 4 + r;
            int col = nh * 128 + j * 16 + ll;
            hnf[rowl * 260 + col] = acc[j][r] + inb[col];
        }
    __syncthreads();
#pragma unroll
    for (int q = 0; q < 8; q++) {
        int rowl = w * 8 + q;
        size_t gidx = (size_t)(m0 + rowl) * HD + l * 4;
        const float* vp = &hnf[rowl * 260 + l * 4];
        float o0 = vp[0], o1 = vp[1], o2 = vp[2], o3 = vp[3];
        float s = o0 + o1 + o2 + o3;
        float s2 = o0 * o0 + o1 * o1 + o2 * o2 + o3 * o3;
#pragma unroll
        for (int mm = 1; mm < 64; mm <<= 1) { s += __shfl_xor(s, mm); s2 += __shfl_xor(s2, mm); }
        float mean = s * (1.f / 256.f);
        float var = s2 * (1.f / 256.f) - mean * mean;
        float rstd = rsqrtf(var + 1e-5f);
        int c = l * 4;
        float4 ov; ov.x = o0; ov.y = o1; ov.z = o2; ov.w = o3;
        *reinterpret_cast<float4*>(h + gidx) = ov;
        ushort4 xo;
        xo.x = f2bf((o0 - mean) * rstd * lng[c + 0] + lnb[c + 0]);
        xo.y = f2bf((o1 - mean) * rstd * lng[c + 1] + lnb[c + 1]);
        xo.z = f2bf((o2 - mean) * rstd * lng[c + 2] + lnb[c + 2]);
        xo.w = f2bf((o3 - mean) * rstd * lng[c + 3] + lnb[c + 3]);
        *reinterpret_cast<ushort4*>(xnb + gidx) = xo;
    }
}

// ---------------- MFMA core with KB=128 register preload ----------------
template <int K>
__device__ __forceinline__ void mfma_kb(const unsigned short* __restrict__ Ap,
                                        const unsigned short* __restrict__ Wp,
                                        f32x4 (*acc)[4]) {
#pragma unroll
    for (int kb = 0; kb < K; kb += 128) {
        short8 af[2][4], bf[4][4];
#pragma unroll
        for (int ks = 0; ks < 4; ks++)
#pragma unroll
            for (int mf = 0; mf < 2; mf++)
                af[mf][ks] = *reinterpret_cast<const short8*>(Ap + (size_t)mf * 16 * K + kb + ks * 32);
#pragma unroll
        for (int ks = 0; ks < 4; ks++)
#pragma unroll
            for (int nf = 0; nf < 4; nf++)
                bf[nf][ks] = *reinterpret_cast<const short8*>(Wp + (size_t)nf * 16 * K + kb + ks * 32);
#pragma unroll
        for (int ks = 0; ks < 4; ks++)
#pragma unroll
            for (int mf = 0; mf < 2; mf++)
#pragma unroll
                for (int nf = 0; nf < 4; nf++)
                    acc[mf][nf] = __builtin_amdgcn_mfma_f32_16x16x32_bf16(af[mf][ks], bf[nf][ks], acc[mf][nf], 0, 0, 0);
    }
}

// ---------------- final GEMM, BM=128, fp32 out ----------------
template <int K, int N>
__global__ __launch_bounds__(256) void gemm_k(const unsigned short* __restrict__ A,
                                              const unsigned short* __restrict__ W,
                                              const float* __restrict__ bias,
                                              float* __restrict__ outf) {
    __shared__ float sf[128 * 68];
    const int tid = threadIdx.x, l = tid & 63, w = tid >> 6;
    const int ll = l & 15, lh = l >> 4;
    const int m0b = blockIdx.x * 128;
    const int m0 = m0b + w * 32;
    const int n0 = blockIdx.y * 64;
    f32x4 acc[2][4] = {};
    mfma_kb<K>(A + (size_t)(m0 + ll) * K + lh * 8, W + (size_t)(n0 + ll) * K + lh * 8, acc);
#pragma unroll
    for (int mf = 0; mf < 2; mf++)
#pragma unroll
        for (int nf = 0; nf < 4; nf++)
#pragma unroll
            for (int r = 0; r < 4; r++) {
                int rowl = w * 32 + mf * 16 + lh * 4 + r;
                int col = nf * 16 + ll;
                sf[rowl * 68 + col] = acc[mf][nf][r] + bias[n0 + col];
            }
    __syncthreads();
#pragma unroll
    for (int p = 0; p < 8; p++) {
        int rowl = p * 16 + (tid >> 4);
        int col = (tid & 15) * 4;
        float4 v = *reinterpret_cast<const float4*>(&sf[rowl * 68 + col]);
        *reinterpret_cast<float4*>(outf + (size_t)(m0b + rowl) * N + n0 + col) = v;
    }
}

// ---------------- fused gate + ip GEMM, BM=128 (grid y: 0..3 gate, 4 = ip) ----------------
__global__ __launch_bounds__(256) void gateip_k(const unsigned short* __restrict__ xnb,
                                                const unsigned short* __restrict__ wg,
                                                const unsigned short* __restrict__ wip,
                                                const float* __restrict__ gbias, const float* __restrict__ ipb,
                                                const float* __restrict__ Bv, const float* __restrict__ bA,
                                                unsigned short* __restrict__ gB, float* __restrict__ u) {
    __shared__ char smem[128 * 68 * 4];
    float* sf = (float*)smem;
    unsigned short* su = (unsigned short*)smem;
    const int tid = threadIdx.x, l = tid & 63, w = tid >> 6;
    const int ll = l & 15, lh = l >> 4;
    const int m0b = blockIdx.x * 128;
    const int m0 = m0b + w * 32;
    const int y = blockIdx.y;
    const bool gate = (y < 4);
    const int n0 = gate ? y * 64 : 0;
    f32x4 acc[2][4] = {};
    mfma_kb<HD>(xnb + (size_t)(m0 + ll) * HD + lh * 8,
                (gate ? wg : wip) + (size_t)(n0 + ll) * HD + lh * 8, acc);
    if (gate) {
#pragma unroll
        for (int mf = 0; mf < 2; mf++)
#pragma unroll
            for (int nf = 0; nf < 4; nf++)
#pragma unroll
                for (int r = 0; r < 4; r++) {
                    int rowl = w * 32 + mf * 16 + lh * 4 + r;
                    int col = nf * 16 + ll;
                    float v = acc[mf][nf][r] + gbias[n0 + col];
                    su[rowl * 72 + col] = f2bf(1.f / (1.f + __expf(-v)));
                }
        __syncthreads();
#pragma unroll
        for (int p = 0; p < 8; p++) {
            int rowl = p * 16 + (tid >> 4);
            int col = (tid & 15) * 4;
            ushort4 v = *reinterpret_cast<const ushort4*>(&su[rowl * 72 + col]);
            *reinterpret_cast<ushort4*>(gB + (size_t)(m0b + rowl) * HD + n0 + col) = v;
        }
    } else {
#pragma unroll
        for (int mf = 0; mf < 2; mf++)
#pragma unroll
            for (int nf = 0; nf < 4; nf++)
#pragma unroll
                for (int r = 0; r < 4; r++) {
                    int rowl = w * 32 + mf * 16 + lh * 4 + r;
                    int col = nf * 16 + ll;
                    float v = acc[mf][nf][r] + ipb[col];
                    sf[rowl * 68 + col] = Bv[col] * v + bA[col];
                }
        __syncthreads();
#pragma unroll
        for (int p = 0; p < 8; p++) {
            int rowl = p * 16 + (tid >> 4);
            int col = (tid & 15) * 4;
            int m = m0b + rowl;           // bt-order
            int t = m & 2047, b2 = m >> 11;
            float4 v = *reinterpret_cast<const float4*>(&sf[rowl * 68 + col]);
            *reinterpret_cast<float4*>(u + ((size_t)((t << 3) + b2)) * 64 + col) = v;
        }
    }
}

// ---------------- fused Cm + proj + blend + LN(next layer) ----------------
template <bool LAST>
__global__ __launch_bounds__(256) void post3_k(const unsigned short* __restrict__ Hs,
                                               const unsigned short* __restrict__ wc,
                                               const float* __restrict__ bC,
                                               const unsigned short* __restrict__ wp,
                                               const float* __restrict__ pb,
                                               const unsigned short* __restrict__ gB,
                                               unsigned short* __restrict__ xnb,
                                               float* __restrict__ h, unsigned short* __restrict__ hb,
                                               const float* __restrict__ lng2, const float* __restrict__ lnb2) {
    __shared__ unsigned short ys[32 * 256];   // XOR-swizzled
    __shared__ float hnf[32 * 264];
    const int tid = threadIdx.x, l = tid & 63, w = tid >> 6;
    const int ll = l & 15, lh = l >> 4;
    const int mf = w >> 1, nh = w & 1;
    const int m0 = blockIdx.x * 32;          // tb-order
    {
        short8 ha[2], cb[8][2];
        const unsigned short* Ap = Hs + (size_t)(m0 + mf * 16 + ll) * SD + lh * 8;
#pragma unroll
        for (int ks = 0; ks < 2; ks++)
            ha[ks] = *reinterpret_cast<const short8*>(Ap + ks * 32);
#pragma unroll
        for (int ks = 0; ks < 2; ks++)
#pragma unroll
            for (int j = 0; j < 8; j++)
                cb[j][ks] = *reinterpret_cast<const short8*>(wc + (size_t)((nh * 8 + j) * 16 + ll) * SD + ks * 32 + lh * 8);
        f32x4 acc[8] = {};
#pragma unroll
        for (int ks = 0; ks < 2; ks++)
#pragma unroll
            for (int j = 0; j < 8; j++)
                acc[j] = __builtin_amdgcn_mfma_f32_16x16x32_bf16(ha[ks], cb[j][ks], acc[j], 0, 0, 0);
#pragma unroll
        for (int j = 0; j < 8; j++)
#pragma unroll
            for (int r = 0; r < 4; r++) {
                int rowl = mf * 16 + lh * 4 + r;
                int col = (nh * 8 + j) * 16 + ll;
                ys[swz(rowl, col, 256)] = f2bf(acc[j][r] + bC[col]);
            }
    }
    __syncthreads();
    {
        f32x4 acc2[8] = {};
        const int arow = mf * 16 + ll;
#pragma unroll
        for (int kb = 0; kb < 2; kb++) {
            short8 pwf[8][4];
#pragma unroll
            for (int ks = 0; ks < 4; ks++)
#pragma unroll
                for (int j = 0; j < 8; j++)
                    pwf[j][ks] = *reinterpret_cast<const short8*>(wp + (size_t)((nh * 8 + j) * 16 + ll) * HD + kb * 128 + ks * 32 + lh * 8);
#pragma unroll
            for (int ks = 0; ks < 4; ks++) {
                int c0 = kb * 128 + ks * 32 + lh * 8;
                short8 a = *reinterpret_cast<const short8*>(&ys[swz(arow, c0, 256)]);
#pragma unroll
                for (int j = 0; j < 8; j++)
                    acc2[j] = __builtin_amdgcn_mfma_f32_16x16x32_bf16(a, pwf[j][ks], acc2[j], 0, 0, 0);
            }
        }
#pragma unroll
        for (int j = 0; j < 8; j++)
#pragma unroll
            for (int r = 0; r < 4; r++) {
                int rowl = mf * 16 + lh * 4 + r;
                int col = (nh * 8 + j) * 16 + ll;
                hnf[rowl * 264 + col] = acc2[j][r] + pb[col];
            }
    }
    __syncthreads();
#pragma unroll
    for (int q = 0; q < 8; q++) {
        int rowl = w * 8 + q;
        int m = m0 + rowl;               // tb-order
        int t = m >> 3, b2 = m & 7;
        size_t gidx = ((size_t)((b2 << 11) + t)) * HD + l * 4;
        float4 hv = *reinterpret_cast<const float4*>(h + gidx);
        ushort4 gv = *reinterpret_cast<const ushort4*>(gB + gidx);
        ushort4 xv = *reinterpret_cast<const ushort4*>(xnb + gidx);
        const float* vp = &hnf[rowl * 264 + l * 4];
        float g0 = bf2f(gv.x), g1 = bf2f(gv.y), g2 = bf2f(gv.z), g3 = bf2f(gv.w);
        float o0 = hv.x + g0 * vp[0] + (1.f - g0) * bf2f(xv.x);
        float o1 = hv.y + g1 * vp[1] + (1.f - g1) * bf2f(xv.y);
        float o2 = hv.z + g2 * vp[2] + (1.f - g2) * bf2f(xv.z);
        float o3 = hv.w + g3 * vp[3] + (1.f - g3) * bf2f(xv.w);
        if constexpr (LAST) {
            ushort4 hbv;
            hbv.x = f2bf(o0); hbv.y = f2bf(o1); hbv.z = f2bf(o2); hbv.w = f2bf(o3);
            *reinterpret_cast<ushort4*>(hb + gidx) = hbv;
        } else {
            float s = o0 + o1 + o2 + o3;
            float s2 = o0 * o0 + o1 * o1 + o2 * o2 + o3 * o3;
#pragma unroll
            for (int mm = 1; mm < 64; mm <<= 1) { s += __shfl_xor(s, mm); s2 += __shfl_xor(s2, mm); }
            float mean = s * (1.f / 256.f);
            float var = s2 * (1.f / 256.f) - mean * mean;
            float rstd = rsqrtf(var + 1e-5f);
            int c = l * 4;
            float4 ov; ov.x = o0; ov.y = o1; ov.z = o2; ov.w = o3;
            *reinterpret_cast<float4*>(h + gidx) = ov;
            ushort4 xo;
            xo.x = f2bf((o0 - mean) * rstd * lng2[c + 0] + lnb2[c + 0]);
            xo.y = f2bf((o1 - mean) * rstd * lng2[c + 1] + lnb2[c + 1]);
            xo.z = f2bf((o2 - mean) * rstd * lng2[c + 2] + lnb2[c + 2]);
            xo.w = f2bf((o3 - mean) * rstd * lng2[c + 3] + lnb2[c + 3]);
            *reinterpret_cast<ushort4*>(xnb + gidx) = xo;
        }
    }
}

// ---------------- scan helpers ----------------
__device__ __forceinline__ void loadA64(const float* __restrict__ Af, int s, float* a) {
#pragma unroll
    for (int q = 0; q < 16; q++) {
        float4 v = reinterpret_cast<const float4*>(Af + s * 64)[q];
        a[q * 4 + 0] = v.x; a[q * 4 + 1] = v.y; a[q * 4 + 2] = v.z; a[q * 4 + 3] = v.w;
    }
}

__device__ __forceinline__ float step64(const float* a, float h, float uu) {
    float ac0 = uu, ac1 = 0.f, ac2 = 0.f, ac3 = 0.f;
#pragma unroll
    for (int k = 0; k < 64; k += 4) {
        float b0 = __int_as_float(__builtin_amdgcn_readlane(__float_as_int(h), k + 0));
        float b1 = __int_as_float(__builtin_amdgcn_readlane(__float_as_int(h), k + 1));
        float b2 = __int_as_float(__builtin_amdgcn_readlane(__float_as_int(h), k + 2));
        float b3 = __int_as_float(__builtin_amdgcn_readlane(__float_as_int(h), k + 3));
        ac0 = fmaf(b0, a[k + 0], ac0);
        ac1 = fmaf(b1, a[k + 1], ac1);
        ac2 = fmaf(b2, a[k + 2], ac2);
        ac3 = fmaf(b3, a[k + 3], ac3);
    }
    return (ac0 + ac1) + (ac2 + ac3);
}

// ---------------- fused scan: chunk -> carry -> replay -> fallback, one dispatch ----------------
__global__ __launch_bounds__(64, 2) void scan_all_k(const float* __restrict__ Af,
                                                    const float* __restrict__ Apow,
                                                    const float* __restrict__ u,
                                                    float* __restrict__ Slast,
                                                    float* __restrict__ Carry,
                                                    unsigned short* __restrict__ Hs,
                                                    int* __restrict__ flag,
                                                    int* __restrict__ bcnt, int* __restrict__ bgen) {
    const int bid = blockIdx.x;
    const int c = bid >> 3, b = bid & 7;
    const int s = threadIdx.x;
    float a[64];
    loadA64(Af, s, a);
    // phase 1: chunk-local linear scan (depth CLEN=32)
    {
        const float* up = u + (size_t)(c * CLEN) * 512 + b * 64 + s;
        float uv[CLEN];
#pragma unroll
        for (int i = 0; i < CLEN; i++) uv[i] = up[(size_t)i * 512];
        float hh = 0.f;
#pragma unroll
        for (int i = 0; i < CLEN; i++) hh = step64(a, hh, uv[i]);
        Slast[bid * 64 + s] = hh;
    }
    gbar(bcnt, bgen, SCAN_BLKS);
    // phase 2: sequential carry (blocks 0..7, one per batch), A^32
    if (bid < 8) {
        float ap[64];
        loadA64(Apow, s, ap);
        float carry = 0.f;
#pragma unroll
        for (int half = 0; half < 2; half++) {
            float sv[32];
#pragma unroll
            for (int j = 0; j < 32; j++) sv[j] = Slast[((half * 32 + j) * 8 + b) * 64 + s];
#pragma unroll
            for (int j = 0; j < 32; j++) {
                Carry[((half * 32 + j) * 8 + b) * 64 + s] = carry;
                carry = step64(ap, carry, sv[j]);
            }
        }
    }
    gbar(bcnt, bgen, SCAN_BLKS);
    // phase 3: replay with true carry + overflow detect
    {
        const float* up = u + (size_t)(c * CLEN) * 512 + b * 64 + s;
        float uv[CLEN];
#pragma unroll
        for (int i = 0; i < CLEN; i++) uv[i] = up[(size_t)i * 512];
        float hh = Carry[bid * 64 + s];
        unsigned short* hp = Hs + (size_t)(c * CLEN) * 512 + b * 64 + s;
        bool bad = false;
#pragma unroll
        for (int i = 0; i < CLEN; i++) {
            hh = step64(a, hh, uv[i]);
            bad |= (fabsf(hh) > 10.f);
            hp[(size_t)i * 512] = f2bf(hh);
        }
        if (__any(bad ? 1 : 0)) {
            if (s == 0) atomicOr(flag, 1);
        }
    }
    gbar(bcnt, bgen, SCAN_BLKS);
    // phase 4: exact clipped fallback if speculation failed (blocks 0..7)
    if (bid < 8) {
        if (__hip_atomic_load(flag, __ATOMIC_ACQUIRE, __HIP_MEMORY_SCOPE_AGENT) != 0) {
            float hh = 0.f;
            for (int t = 0; t < T_LEN; t++) {
                float uu = u[((size_t)(t << 3) + b) * 64 + s];
                float hp2 = step64(a, hh, uu);
                hh = fminf(fmaxf(hp2, -10.f), 10.f);
                Hs[((size_t)(t << 3) + b) * 64 + s] = f2bf(hh);
            }
        }
    }
}

// ---------------- launch ----------------
extern "C" void kernel_launch(void* const* d_in, const int* in_sizes, int n_in,
                              void* d_out, int out_size, void* d_ws, size_t ws_size,
                              hipStream_t stream) {
    const float* x    = (const float*)d_in[0];
    const float* inw  = (const float*)d_in[1];
    const float* inb  = (const float*)d_in[2];
    const float* lng  = (const float*)d_in[3];
    const float* lnb  = (const float*)d_in[4];
    const float* ipw  = (const float*)d_in[5];
    const float* ipb  = (const float*)d_in[6];
    const float* Amat = (const float*)d_in[7];
    const float* Bv   = (const float*)d_in[8];
    const float* Cm   = (const float*)d_in[9];
    const float* bA   = (const float*)d_in[10];
    const float* bC   = (const float*)d_in[11];
    const float* gw   = (const float*)d_in[12];
    const float* gbia = (const float*)d_in[13];
    const float* pw   = (const float*)d_in[14];
    const float* pb   = (const float*)d_in[15];
    const float* ow   = (const float*)d_in[16];
    const float* ob   = (const float*)d_in[17];

    char* ws = (char*)d_ws;
    float*          u  = (float*)(ws + 0);                   // 4 MB
    unsigned short* Hs = (unsigned short*)(ws + 4194304);    // 2 MB
    unsigned short* hb = (unsigned short*)(ws + 14680064);   // 8 MB
    unsigned short* wb = (unsigned short*)(ws + 25165824);   // 2 MB
    float*          h  = (float*)(ws + 27262976);            // 16 MB
    unsigned short* xnb = (unsigned short*)(ws + 44040192);  // 8 MB
    unsigned short* gB  = (unsigned short*)(ws + 52428800);  // 8 MB

    char* sc = (char*)d_out;   // small scratch; fully overwritten by final GEMM
    float* Apow  = (float*)(sc + 0);          // 64 KB: [4][64][64] (A^32)
    float* Slast = (float*)(sc + 65536);      // 128 KB: [64*8][64]
    float* Carry = (float*)(sc + 196608);     // 128 KB
    int*   flag  = (int*)(sc + 327680);       // 16 B (per-layer)
    int*   bcnt  = (int*)(sc + 327696);       // 4 B
    int*   bgen  = (int*)(sc + 327700);       // 4 B

    const unsigned short* w_in = wb + 0;
    const unsigned short* w_ip = wb + 196608;
    const unsigned short* w_g  = wb + 262144;
    const unsigned short* w_p  = wb + 524288;
    const unsigned short* w_c  = wb + 786432;
    const unsigned short* w_o  = wb + 851968;

    hipMemsetAsync(sc + 327680, 0, 24, stream);  // flags + barrier cnt/gen (gen value irrelevant, cnt must be 0)
    cvt_w_k<<<4096, 256, 0, stream>>>(inw, ipw, gw, pw, Cm, ow, wb);
    matpow_k<<<4, 256, 0, stream>>>(Amat, Apow);

    in_ln_k<<<512, 256, 0, stream>>>(x, w_in, inb, lng, lnb, h, xnb);
    for (int i = 0; i < 4; i++) {
        gateip_k<<<dim3(128, 5), 256, 0, stream>>>(xnb, w_g + i * 65536, w_ip + i * 16384,
                                                   gbia + i * HD, ipb + i * SD,
                                                   Bv + i * SD, bA + i * SD, gB, u);
        scan_all_k<<<SCAN_BLKS, 64, 0, stream>>>(Amat + i * 4096, Apow + i * 4096, u,
                                                 Slast, Carry, Hs, flag + i, bcnt, bgen);
        if (i < 3)
            post3_k<false><<<512, 256, 0, stream>>>(Hs, w_c + i * 16384, bC + i * HD,
                                                    w_p + i * 65536, pb + i * HD, gB, xnb, h, hb,
                                                    lng + (i + 1) * HD, lnb + (i + 1) * HD);
        else
            post3_k<true><<<512, 256, 0, stream>>>(Hs, w_c + i * 16384, bC + i * HD,
                                                   w_p + i * 65536, pb + i * HD, gB, xnb, h, hb,
                                                   lng, lnb);
    }
    gemm_k<HD, DOUT><<<dim3(128, 12), 256, 0, stream>>>(hb, w_o, ob, (float*)d_out);
}

// Round 10
// 511.425 us; speedup vs baseline: 2.4000x; 2.4000x over previous
//
#include <hip/hip_runtime.h>

typedef float f32x4 __attribute__((ext_vector_type(4)));
typedef short short8 __attribute__((ext_vector_type(8)));

#define T_LEN 2048
#define HD 256
#define SD 64
#define DIN 768
#define DOUT 768
#define NCHUNK 32
#define CLEN 64

__device__ __forceinline__ unsigned short f2bf(float f) {
    unsigned int u = __float_as_uint(f);
    unsigned int r = u + 0x7FFFu + ((u >> 16) & 1u);
    return (unsigned short)(r >> 16);
}
__device__ __forceinline__ float bf2f(unsigned short h) {
    return __uint_as_float(((unsigned int)h) << 16);
}
__device__ __forceinline__ int swz(int row, int col, int stride) {
    return row * stride + (col ^ ((row & 7) << 3));
}

// ---------------- weight conversion ----------------
__global__ __launch_bounds__(256) void cvt_w_k(const float* __restrict__ s0, const float* __restrict__ s1,
                                               const float* __restrict__ s2, const float* __restrict__ s3,
                                               const float* __restrict__ s4, const float* __restrict__ s5,
                                               unsigned short* __restrict__ d) {
    int i = blockIdx.x * 256 + threadIdx.x;
    if (i >= 1048576) return;
    float v;
    if (i < 196608)      v = s0[i];
    else if (i < 262144) v = s1[i - 196608];
    else if (i < 524288) v = s2[i - 262144];
    else if (i < 786432) v = s3[i - 524288];
    else if (i < 851968) v = s4[i - 786432];
    else                 v = s5[i - 851968];
    d[i] = f2bf(v);
}

// ---------------- A^64 via bf16-split MFMA (6 squarings, verified) ----------------
__global__ __launch_bounds__(256) void matpow_k(const float* __restrict__ A, float* __restrict__ Apow) {
    __shared__ unsigned short Mh[4096], Ml[4096], MhT[4096], MlT[4096];
    const int l = blockIdx.x, tid = threadIdx.x;
    const int w = tid >> 6, ln = tid & 63, ll = ln & 15, lh = ln >> 4;
    const float* src = A + l * 4096;
    for (int i = tid; i < 4096; i += 256) {
        float v = src[i];
        unsigned short hi = f2bf(v);
        unsigned short lo = f2bf(v - bf2f(hi));
        int r = i >> 6, c = i & 63;
        Mh[swz(r, c, 64)] = hi;  Ml[swz(r, c, 64)] = lo;
        MhT[swz(c, r, 64)] = hi; MlT[swz(c, r, 64)] = lo;
    }
    __syncthreads();
    for (int it = 0; it < 6; it++) {
        f32x4 acc[4] = {};
#pragma unroll
        for (int ks = 0; ks < 2; ks++) {
            int ar = w * 16 + ll, c0 = ks * 32 + lh * 8;
            short8 ah = *reinterpret_cast<const short8*>(&Mh[swz(ar, c0, 64)]);
            short8 al = *reinterpret_cast<const short8*>(&Ml[swz(ar, c0, 64)]);
#pragma unroll
            for (int nf = 0; nf < 4; nf++) {
                int br = nf * 16 + ll;
                short8 bh = *reinterpret_cast<const short8*>(&MhT[swz(br, c0, 64)]);
                short8 bl = *reinterpret_cast<const short8*>(&MlT[swz(br, c0, 64)]);
                acc[nf] = __builtin_amdgcn_mfma_f32_16x16x32_bf16(ah, bh, acc[nf], 0, 0, 0);
                acc[nf] = __builtin_amdgcn_mfma_f32_16x16x32_bf16(ah, bl, acc[nf], 0, 0, 0);
                acc[nf] = __builtin_amdgcn_mfma_f32_16x16x32_bf16(al, bh, acc[nf], 0, 0, 0);
            }
        }
        __syncthreads();
#pragma unroll
        for (int nf = 0; nf < 4; nf++)
#pragma unroll
            for (int r = 0; r < 4; r++) {
                float v = acc[nf][r];
                int row = w * 16 + lh * 4 + r, col = nf * 16 + ll;
                unsigned short hi = f2bf(v);
                unsigned short lo = f2bf(v - bf2f(hi));
                Mh[swz(row, col, 64)] = hi;  Ml[swz(row, col, 64)] = lo;
                MhT[swz(col, row, 64)] = hi; MlT[swz(col, row, 64)] = lo;
            }
        __syncthreads();
    }
    for (int i = tid; i < 4096; i += 256) {
        int r = i >> 6, c = i & 63;
        Apow[l * 4096 + i] = bf2f(Mh[swz(r, c, 64)]) + bf2f(Ml[swz(r, c, 64)]);
    }
}

// ---------------- fused in-proj (fp32 x direct) + LN, BM=32, full N=256 ----------------
__global__ __launch_bounds__(256) void in_ln_k(const float* __restrict__ x,
                                               const unsigned short* __restrict__ w_in,
                                               const float* __restrict__ inb,
                                               const float* __restrict__ lng, const float* __restrict__ lnb,
                                               float* __restrict__ h, unsigned short* __restrict__ xnb) {
    __shared__ float hnf[32 * 260];
    const int tid = threadIdx.x, l = tid & 63, w = tid >> 6;
    const int ll = l & 15, lh = l >> 4;
    const int mf = w >> 1, nh = w & 1;
    const int m0 = blockIdx.x * 32;
    const float* Ap = x + (size_t)(m0 + mf * 16 + ll) * DIN + lh * 8;
    const unsigned short* Wp = w_in + (size_t)(nh * 128 + ll) * DIN + lh * 8;
    f32x4 acc[8] = {};
#pragma unroll
    for (int kb = 0; kb < DIN; kb += 128) {
        short8 af[4];
#pragma unroll
        for (int ks = 0; ks < 4; ks++) {
            float4 a0 = *reinterpret_cast<const float4*>(Ap + kb + ks * 32);
            float4 a1 = *reinterpret_cast<const float4*>(Ap + kb + ks * 32 + 4);
            short8 t;
            t[0] = (short)f2bf(a0.x); t[1] = (short)f2bf(a0.y);
            t[2] = (short)f2bf(a0.z); t[3] = (short)f2bf(a0.w);
            t[4] = (short)f2bf(a1.x); t[5] = (short)f2bf(a1.y);
            t[6] = (short)f2bf(a1.z); t[7] = (short)f2bf(a1.w);
            af[ks] = t;
        }
#pragma unroll
        for (int half = 0; half < 2; half++) {
            short8 bfx[8][2];
#pragma unroll
            for (int ks = 0; ks < 2; ks++)
#pragma unroll
                for (int j = 0; j < 8; j++)
                    bfx[j][ks] = *reinterpret_cast<const short8*>(Wp + (size_t)(j * 16) * DIN + kb + (half * 2 + ks) * 32);
#pragma unroll
            for (int ks = 0; ks < 2; ks++)
#pragma unroll
                for (int j = 0; j < 8; j++)
                    acc[j] = __builtin_amdgcn_mfma_f32_16x16x32_bf16(af[half * 2 + ks], bfx[j][ks], acc[j], 0, 0, 0);
        }
    }
#pragma unroll
    for (int j = 0; j < 8; j++)
#pragma unroll
        for (int r = 0; r < 4; r++) {
            int rowl = mf * 16 + lh * 4 + r;
            int col = nh * 128 + j * 16 + ll;
            hnf[rowl * 260 + col] = acc[j][r] + inb[col];
        }
    __syncthreads();
#pragma unroll
    for (int q = 0; q < 8; q++) {
        int rowl = w * 8 + q;
        size_t gidx = (size_t)(m0 + rowl) * HD + l * 4;
        const float* vp = &hnf[rowl * 260 + l * 4];
        float o0 = vp[0], o1 = vp[1], o2 = vp[2], o3 = vp[3];
        float s = o0 + o1 + o2 + o3;
        float s2 = o0 * o0 + o1 * o1 + o2 * o2 + o3 * o3;
#pragma unroll
        for (int mm = 1; mm < 64; mm <<= 1) { s += __shfl_xor(s, mm); s2 += __shfl_xor(s2, mm); }
        float mean = s * (1.f / 256.f);
        float var = s2 * (1.f / 256.f) - mean * mean;
        float rstd = rsqrtf(var + 1e-5f);
        int c = l * 4;
        float4 ov; ov.x = o0; ov.y = o1; ov.z = o2; ov.w = o3;
        *reinterpret_cast<float4*>(h + gidx) = ov;
        ushort4 xo;
        xo.x = f2bf((o0 - mean) * rstd * lng[c + 0] + lnb[c + 0]);
        xo.y = f2bf((o1 - mean) * rstd * lng[c + 1] + lnb[c + 1]);
        xo.z = f2bf((o2 - mean) * rstd * lng[c + 2] + lnb[c + 2]);
        xo.w = f2bf((o3 - mean) * rstd * lng[c + 3] + lnb[c + 3]);
        *reinterpret_cast<ushort4*>(xnb + gidx) = xo;
    }
}

// ---------------- MFMA core with KB=128 register preload ----------------
template <int K>
__device__ __forceinline__ void mfma_kb(const unsigned short* __restrict__ Ap,
                                        const unsigned short* __restrict__ Wp,
                                        f32x4 (*acc)[4]) {
#pragma unroll
    for (int kb = 0; kb < K; kb += 128) {
        short8 af[2][4], bf[4][4];
#pragma unroll
        for (int ks = 0; ks < 4; ks++)
#pragma unroll
            for (int mf = 0; mf < 2; mf++)
                af[mf][ks] = *reinterpret_cast<const short8*>(Ap + (size_t)mf * 16 * K + kb + ks * 32);
#pragma unroll
        for (int ks = 0; ks < 4; ks++)
#pragma unroll
            for (int nf = 0; nf < 4; nf++)
                bf[nf][ks] = *reinterpret_cast<const short8*>(Wp + (size_t)nf * 16 * K + kb + ks * 32);
#pragma unroll
        for (int ks = 0; ks < 4; ks++)
#pragma unroll
            for (int mf = 0; mf < 2; mf++)
#pragma unroll
                for (int nf = 0; nf < 4; nf++)
                    acc[mf][nf] = __builtin_amdgcn_mfma_f32_16x16x32_bf16(af[mf][ks], bf[nf][ks], acc[mf][nf], 0, 0, 0);
    }
}

// ---------------- final GEMM, BM=128, fp32 out, nontemporal stores ----------------
template <int K, int N>
__global__ __launch_bounds__(256) void gemm_k(const unsigned short* __restrict__ A,
                                              const unsigned short* __restrict__ W,
                                              const float* __restrict__ bias,
                                              float* __restrict__ outf) {
    __shared__ float sf[128 * 68];
    const int tid = threadIdx.x, l = tid & 63, w = tid >> 6;
    const int ll = l & 15, lh = l >> 4;
    const int m0b = blockIdx.x * 128;
    const int m0 = m0b + w * 32;
    const int n0 = blockIdx.y * 64;
    f32x4 acc[2][4] = {};
    mfma_kb<K>(A + (size_t)(m0 + ll) * K + lh * 8, W + (size_t)(n0 + ll) * K + lh * 8, acc);
#pragma unroll
    for (int mf = 0; mf < 2; mf++)
#pragma unroll
        for (int nf = 0; nf < 4; nf++)
#pragma unroll
            for (int r = 0; r < 4; r++) {
                int rowl = w * 32 + mf * 16 + lh * 4 + r;
                int col = nf * 16 + ll;
                sf[rowl * 68 + col] = acc[mf][nf][r] + bias[n0 + col];
            }
    __syncthreads();
#pragma unroll
    for (int p = 0; p < 8; p++) {
        int rowl = p * 16 + (tid >> 4);
        int col = (tid & 15) * 4;
        f32x4 v = *reinterpret_cast<const f32x4*>(&sf[rowl * 68 + col]);
        __builtin_nontemporal_store(v, reinterpret_cast<f32x4*>(outf + (size_t)(m0b + rowl) * N + n0 + col));
    }
}

// ---------------- fused gate + ip GEMM, BM=128 (grid y: 0..3 gate, 4 = ip) ----------------
__global__ __launch_bounds__(256) void gateip_k(const unsigned short* __restrict__ xnb,
                                                const unsigned short* __restrict__ wg,
                                                const unsigned short* __restrict__ wip,
                                                const float* __restrict__ gbias, const float* __restrict__ ipb,
                                                const float* __restrict__ Bv, const float* __restrict__ bA,
                                                unsigned short* __restrict__ gB, float* __restrict__ u) {
    __shared__ char smem[128 * 68 * 4];
    float* sf = (float*)smem;
    unsigned short* su = (unsigned short*)smem;
    const int tid = threadIdx.x, l = tid & 63, w = tid >> 6;
    const int ll = l & 15, lh = l >> 4;
    const int m0b = blockIdx.x * 128;
    const int m0 = m0b + w * 32;
    const int y = blockIdx.y;
    const bool gate = (y < 4);
    const int n0 = gate ? y * 64 : 0;
    f32x4 acc[2][4] = {};
    mfma_kb<HD>(xnb + (size_t)(m0 + ll) * HD + lh * 8,
                (gate ? wg : wip) + (size_t)(n0 + ll) * HD + lh * 8, acc);
    if (gate) {
#pragma unroll
        for (int mf = 0; mf < 2; mf++)
#pragma unroll
            for (int nf = 0; nf < 4; nf++)
#pragma unroll
                for (int r = 0; r < 4; r++) {
                    int rowl = w * 32 + mf * 16 + lh * 4 + r;
                    int col = nf * 16 + ll;
                    float v = acc[mf][nf][r] + gbias[n0 + col];
                    su[rowl * 72 + col] = f2bf(1.f / (1.f + __expf(-v)));
                }
        __syncthreads();
#pragma unroll
        for (int p = 0; p < 8; p++) {
            int rowl = p * 16 + (tid >> 4);
            int col = (tid & 15) * 4;
            ushort4 v = *reinterpret_cast<const ushort4*>(&su[rowl * 72 + col]);
            *reinterpret_cast<ushort4*>(gB + (size_t)(m0b + rowl) * HD + n0 + col) = v;
        }
    } else {
#pragma unroll
        for (int mf = 0; mf < 2; mf++)
#pragma unroll
            for (int nf = 0; nf < 4; nf++)
#pragma unroll
                for (int r = 0; r < 4; r++) {
                    int rowl = w * 32 + mf * 16 + lh * 4 + r;
                    int col = nf * 16 + ll;
                    float v = acc[mf][nf][r] + ipb[col];
                    sf[rowl * 68 + col] = Bv[col] * v + bA[col];
                }
        __syncthreads();
#pragma unroll
        for (int p = 0; p < 8; p++) {
            int rowl = p * 16 + (tid >> 4);
            int col = (tid & 15) * 4;
            int m = m0b + rowl;           // bt-order
            int t = m & 2047, b2 = m >> 11;
            float4 v = *reinterpret_cast<const float4*>(&sf[rowl * 68 + col]);
            *reinterpret_cast<float4*>(u + ((size_t)((t << 3) + b2)) * 64 + col) = v;
        }
    }
}

// ---------------- fused Cm + proj + blend + LN(next layer) ----------------
template <bool LAST>
__global__ __launch_bounds__(256) void post3_k(const unsigned short* __restrict__ Hs,
                                               const unsigned short* __restrict__ wc,
                                               const float* __restrict__ bC,
                                               const unsigned short* __restrict__ wp,
                                               const float* __restrict__ pb,
                                               const unsigned short* __restrict__ gB,
                                               unsigned short* __restrict__ xnb,
                                               float* __restrict__ h, unsigned short* __restrict__ hb,
                                               const float* __restrict__ lng2, const float* __restrict__ lnb2) {
    __shared__ unsigned short ys[32 * 256];   // XOR-swizzled
    __shared__ float hnf[32 * 264];
    const int tid = threadIdx.x, l = tid & 63, w = tid >> 6;
    const int ll = l & 15, lh = l >> 4;
    const int mf = w >> 1, nh = w & 1;
    const int m0 = blockIdx.x * 32;          // tb-order
    {
        short8 ha[2], cb[8][2];
        const unsigned short* Ap = Hs + (size_t)(m0 + mf * 16 + ll) * SD + lh * 8;
#pragma unroll
        for (int ks = 0; ks < 2; ks++)
            ha[ks] = *reinterpret_cast<const short8*>(Ap + ks * 32);
#pragma unroll
        for (int ks = 0; ks < 2; ks++)
#pragma unroll
            for (int j = 0; j < 8; j++)
                cb[j][ks] = *reinterpret_cast<const short8*>(wc + (size_t)((nh * 8 + j) * 16 + ll) * SD + ks * 32 + lh * 8);
        f32x4 acc[8] = {};
#pragma unroll
        for (int ks = 0; ks < 2; ks++)
#pragma unroll
            for (int j = 0; j < 8; j++)
                acc[j] = __builtin_amdgcn_mfma_f32_16x16x32_bf16(ha[ks], cb[j][ks], acc[j], 0, 0, 0);
#pragma unroll
        for (int j = 0; j < 8; j++)
#pragma unroll
            for (int r = 0; r < 4; r++) {
                int rowl = mf * 16 + lh * 4 + r;
                int col = (nh * 8 + j) * 16 + ll;
                ys[swz(rowl, col, 256)] = f2bf(acc[j][r] + bC[col]);
            }
    }
    __syncthreads();
    {
        f32x4 acc2[8] = {};
        const int arow = mf * 16 + ll;
#pragma unroll
        for (int kb = 0; kb < 2; kb++) {
            short8 pwf[8][4];
#pragma unroll
            for (int ks = 0; ks < 4; ks++)
#pragma unroll
                for (int j = 0; j < 8; j++)
                    pwf[j][ks] = *reinterpret_cast<const short8*>(wp + (size_t)((nh * 8 + j) * 16 + ll) * HD + kb * 128 + ks * 32 + lh * 8);
#pragma unroll
            for (int ks = 0; ks < 4; ks++) {
                int c0 = kb * 128 + ks * 32 + lh * 8;
                short8 a = *reinterpret_cast<const short8*>(&ys[swz(arow, c0, 256)]);
#pragma unroll
                for (int j = 0; j < 8; j++)
                    acc2[j] = __builtin_amdgcn_mfma_f32_16x16x32_bf16(a, pwf[j][ks], acc2[j], 0, 0, 0);
            }
        }
#pragma unroll
        for (int j = 0; j < 8; j++)
#pragma unroll
            for (int r = 0; r < 4; r++) {
                int rowl = mf * 16 + lh * 4 + r;
                int col = (nh * 8 + j) * 16 + ll;
                hnf[rowl * 264 + col] = acc2[j][r] + pb[col];
            }
    }
    __syncthreads();
#pragma unroll
    for (int q = 0; q < 8; q++) {
        int rowl = w * 8 + q;
        int m = m0 + rowl;               // tb-order
        int t = m >> 3, b2 = m & 7;
        size_t gidx = ((size_t)((b2 << 11) + t)) * HD + l * 4;
        float4 hv = *reinterpret_cast<const float4*>(h + gidx);
        ushort4 gv = *reinterpret_cast<const ushort4*>(gB + gidx);
        ushort4 xv = *reinterpret_cast<const ushort4*>(xnb + gidx);
        const float* vp = &hnf[rowl * 264 + l * 4];
        float g0 = bf2f(gv.x), g1 = bf2f(gv.y), g2 = bf2f(gv.z), g3 = bf2f(gv.w);
        float o0 = hv.x + g0 * vp[0] + (1.f - g0) * bf2f(xv.x);
        float o1 = hv.y + g1 * vp[1] + (1.f - g1) * bf2f(xv.y);
        float o2 = hv.z + g2 * vp[2] + (1.f - g2) * bf2f(xv.z);
        float o3 = hv.w + g3 * vp[3] + (1.f - g3) * bf2f(xv.w);
        if constexpr (LAST) {
            ushort4 hbv;
            hbv.x = f2bf(o0); hbv.y = f2bf(o1); hbv.z = f2bf(o2); hbv.w = f2bf(o3);
            *reinterpret_cast<ushort4*>(hb + gidx) = hbv;
        } else {
            float s = o0 + o1 + o2 + o3;
            float s2 = o0 * o0 + o1 * o1 + o2 * o2 + o3 * o3;
#pragma unroll
            for (int mm = 1; mm < 64; mm <<= 1) { s += __shfl_xor(s, mm); s2 += __shfl_xor(s2, mm); }
            float mean = s * (1.f / 256.f);
            float var = s2 * (1.f / 256.f) - mean * mean;
            float rstd = rsqrtf(var + 1e-5f);
            int c = l * 4;
            float4 ov; ov.x = o0; ov.y = o1; ov.z = o2; ov.w = o3;
            *reinterpret_cast<float4*>(h + gidx) = ov;
            ushort4 xo;
            xo.x = f2bf((o0 - mean) * rstd * lng2[c + 0] + lnb2[c + 0]);
            xo.y = f2bf((o1 - mean) * rstd * lng2[c + 1] + lnb2[c + 1]);
            xo.z = f2bf((o2 - mean) * rstd * lng2[c + 2] + lnb2[c + 2]);
            xo.w = f2bf((o3 - mean) * rstd * lng2[c + 3] + lnb2[c + 3]);
            *reinterpret_cast<ushort4*>(xnb + gidx) = xo;
        }
    }
}

// ---------------- scan helpers ----------------
__device__ __forceinline__ void loadA64(const float* __restrict__ Af, int s, float* a) {
#pragma unroll
    for (int q = 0; q < 16; q++) {
        float4 v = reinterpret_cast<const float4*>(Af + s * 64)[q];
        a[q * 4 + 0] = v.x; a[q * 4 + 1] = v.y; a[q * 4 + 2] = v.z; a[q * 4 + 3] = v.w;
    }
}

__device__ __forceinline__ float step64(const float* a, float h, float uu) {
    float ac0 = uu, ac1 = 0.f, ac2 = 0.f, ac3 = 0.f;
#pragma unroll
    for (int k = 0; k < 64; k += 4) {
        float b0 = __int_as_float(__builtin_amdgcn_readlane(__float_as_int(h), k + 0));
        float b1 = __int_as_float(__builtin_amdgcn_readlane(__float_as_int(h), k + 1));
        float b2 = __int_as_float(__builtin_amdgcn_readlane(__float_as_int(h), k + 2));
        float b3 = __int_as_float(__builtin_amdgcn_readlane(__float_as_int(h), k + 3));
        ac0 = fmaf(b0, a[k + 0], ac0);
        ac1 = fmaf(b1, a[k + 1], ac1);
        ac2 = fmaf(b2, a[k + 2], ac2);
        ac3 = fmaf(b3, a[k + 3], ac3);
    }
    return (ac0 + ac1) + (ac2 + ac3);
}

__global__ __launch_bounds__(64) void scan_chunk_k(const float* __restrict__ Af,
                                                   const float* __restrict__ u,
                                                   float* __restrict__ Slast) {
    const int c = blockIdx.x >> 3, b = blockIdx.x & 7;
    const int s = threadIdx.x;
    float a[64];
    loadA64(Af, s, a);
    const float* up = u + (c * CLEN) * 512 + b * 64 + s;
    float uv[CLEN];
#pragma unroll
    for (int i = 0; i < CLEN; i++) uv[i] = up[i * 512];
    float h = 0.f;
#pragma unroll
    for (int i = 0; i < CLEN; i++) h = step64(a, h, uv[i]);
    Slast[blockIdx.x * 64 + s] = h;
}

__global__ __launch_bounds__(64) void carry_k(const float* __restrict__ Apow,
                                              const float* __restrict__ Slast,
                                              float* __restrict__ Carry) {
    const int b = blockIdx.x;
    const int s = threadIdx.x;
    float a[64];
    loadA64(Apow, s, a);
    float sv[NCHUNK];
#pragma unroll
    for (int c = 0; c < NCHUNK; c++) sv[c] = Slast[(c * 8 + b) * 64 + s];
    float carry = 0.f;
#pragma unroll
    for (int c = 0; c < NCHUNK; c++) {
        Carry[(c * 8 + b) * 64 + s] = carry;
        carry = step64(a, carry, sv[c]);
    }
}

__global__ __launch_bounds__(64) void replay_k(const float* __restrict__ Af,
                                               const float* __restrict__ u,
                                               const float* __restrict__ Carry,
                                               unsigned short* __restrict__ Hs,
                                               int* __restrict__ flag) {
    const int c = blockIdx.x >> 3, b = blockIdx.x & 7;
    const int s = threadIdx.x;
    float a[64];
    loadA64(Af, s, a);
    const float* up = u + (c * CLEN) * 512 + b * 64 + s;
    float uv[CLEN];
#pragma unroll
    for (int i = 0; i < CLEN; i++) uv[i] = up[i * 512];
    float h = Carry[blockIdx.x * 64 + s];
    unsigned short* hp = Hs + (c * CLEN) * 512 + b * 64 + s;
    bool bad = false;
#pragma unroll
    for (int i = 0; i < CLEN; i++) {
        h = step64(a, h, uv[i]);
        bad |= (fabsf(h) > 10.f);
        hp[i * 512] = f2bf(h);
    }
    if (__any(bad ? 1 : 0)) {
        if (s == 0) atomicOr(flag, 1);
    }
}

__global__ __launch_bounds__(64) void scan_seq_k(const float* __restrict__ Af,
                                                 const float* __restrict__ u,
                                                 unsigned short* __restrict__ Hs,
                                                 const int* __restrict__ flag) {
    if (*flag == 0) return;
    const int b = blockIdx.x;
    const int s = threadIdx.x;
    float a[64];
    loadA64(Af, s, a);
    float h = 0.f;
    for (int t = 0; t < T_LEN; t++) {
        float uu = u[((t << 3) + b) * 64 + s];
        float hp = step64(a, h, uu);
        h = fminf(fmaxf(hp, -10.f), 10.f);
        Hs[((t << 3) + b) * 64 + s] = f2bf(h);
    }
}

// ---------------- launch ----------------
extern "C" void kernel_launch(void* const* d_in, const int* in_sizes, int n_in,
                              void* d_out, int out_size, void* d_ws, size_t ws_size,
                              hipStream_t stream) {
    const float* x    = (const float*)d_in[0];
    const float* inw  = (const float*)d_in[1];
    const float* inb  = (const float*)d_in[2];
    const float* lng  = (const float*)d_in[3];
    const float* lnb  = (const float*)d_in[4];
    const float* ipw  = (const float*)d_in[5];
    const float* ipb  = (const float*)d_in[6];
    const float* Amat = (const float*)d_in[7];
    const float* Bv   = (const float*)d_in[8];
    const float* Cm   = (const float*)d_in[9];
    const float* bA   = (const float*)d_in[10];
    const float* bC   = (const float*)d_in[11];
    const float* gw   = (const float*)d_in[12];
    const float* gbia = (const float*)d_in[13];
    const float* pw   = (const float*)d_in[14];
    const float* pb   = (const float*)d_in[15];
    const float* ow   = (const float*)d_in[16];
    const float* ob   = (const float*)d_in[17];

    char* ws = (char*)d_ws;
    float*          u  = (float*)(ws + 0);                   // 4 MB
    unsigned short* Hs = (unsigned short*)(ws + 4194304);    // 2 MB
    unsigned short* hb = (unsigned short*)(ws + 14680064);   // 8 MB
    unsigned short* wb = (unsigned short*)(ws + 25165824);   // 2 MB
    float*          h  = (float*)(ws + 27262976);            // 16 MB
    unsigned short* xnb = (unsigned short*)(ws + 44040192);  // 8 MB
    unsigned short* gB  = (unsigned short*)(ws + 52428800);  // 8 MB

    char* sc = (char*)d_out;   // small scratch; fully overwritten by final GEMM
    float* Apow  = (float*)(sc + 0);          // 64 KB: [4][64][64] (A^64)
    float* Slast = (float*)(sc + 65536);      // 64 KB
    float* Carry = (float*)(sc + 131072);     // 64 KB
    int*   flag  = (int*)(sc + 196608);       // 16 B

    const unsigned short* w_in = wb + 0;
    const unsigned short* w_ip = wb + 196608;
    const unsigned short* w_g  = wb + 262144;
    const unsigned short* w_p  = wb + 524288;
    const unsigned short* w_c  = wb + 786432;
    const unsigned short* w_o  = wb + 851968;

    hipMemsetAsync(flag, 0, 16, stream);
    cvt_w_k<<<4096, 256, 0, stream>>>(inw, ipw, gw, pw, Cm, ow, wb);
    matpow_k<<<4, 256, 0, stream>>>(Amat, Apow);

    in_ln_k<<<512, 256, 0, stream>>>(x, w_in, inb, lng, lnb, h, xnb);
    for (int i = 0; i < 4; i++) {
        gateip_k<<<dim3(128, 5), 256, 0, stream>>>(xnb, w_g + i * 65536, w_ip + i * 16384,
                                                   gbia + i * HD, ipb + i * SD,
                                                   Bv + i * SD, bA + i * SD, gB, u);
        scan_chunk_k<<<256, 64, 0, stream>>>(Amat + i * 4096, u, Slast);
        carry_k<<<8, 64, 0, stream>>>(Apow + i * 4096, Slast, Carry);
        replay_k<<<256, 64, 0, stream>>>(Amat + i * 4096, u, Carry, Hs, flag + i);
        scan_seq_k<<<8, 64, 0, stream>>>(Amat + i * 4096, u, Hs, flag + i);
        if (i < 3)
            post3_k<false><<<512, 256, 0, stream>>>(Hs, w_c + i * 16384, bC + i * HD,
                                                    w_p + i * 65536, pb + i * HD, gB, xnb, h, hb,
                                                    lng + (i + 1) * HD, lnb + (i + 1) * HD);
        else
            post3_k<true><<<512, 256, 0, stream>>>(Hs, w_c + i * 16384, bC + i * HD,
                                                   w_p + i * 65536, pb + i * HD, gB, xnb, h, hb,
                                                   lng, lnb);
    }
    gemm_k<HD, DOUT><<<dim3(128, 12), 256, 0, stream>>>(hb, w_o, ob, (float*)d_out);
}

// Round 11
// 506.678 us; speedup vs baseline: 2.4225x; 1.0094x over previous
//
#include <hip/hip_runtime.h>

typedef float f32x4 __attribute__((ext_vector_type(4)));
typedef short short8 __attribute__((ext_vector_type(8)));

#define T_LEN 2048
#define HD 256
#define SD 64
#define DIN 768
#define DOUT 768
#define NCHUNK 32
#define CLEN 64

#define SBAR() __builtin_amdgcn_sched_barrier(0)

__device__ __forceinline__ unsigned short f2bf(float f) {
    unsigned int u = __float_as_uint(f);
    unsigned int r = u + 0x7FFFu + ((u >> 16) & 1u);
    return (unsigned short)(r >> 16);
}
__device__ __forceinline__ float bf2f(unsigned short h) {
    return __uint_as_float(((unsigned int)h) << 16);
}
__device__ __forceinline__ int swz(int row, int col, int stride) {
    return row * stride + (col ^ ((row & 7) << 3));
}

// ---------------- weight conversion ----------------
__global__ __launch_bounds__(256) void cvt_w_k(const float* __restrict__ s0, const float* __restrict__ s1,
                                               const float* __restrict__ s2, const float* __restrict__ s3,
                                               const float* __restrict__ s4, const float* __restrict__ s5,
                                               unsigned short* __restrict__ d) {
    int i = blockIdx.x * 256 + threadIdx.x;
    if (i >= 1048576) return;
    float v;
    if (i < 196608)      v = s0[i];
    else if (i < 262144) v = s1[i - 196608];
    else if (i < 524288) v = s2[i - 262144];
    else if (i < 786432) v = s3[i - 524288];
    else if (i < 851968) v = s4[i - 786432];
    else                 v = s5[i - 851968];
    d[i] = f2bf(v);
}

// ---------------- A^64 via bf16-split MFMA (6 squarings, verified) ----------------
__global__ __launch_bounds__(256) void matpow_k(const float* __restrict__ A, float* __restrict__ Apow) {
    __shared__ unsigned short Mh[4096], Ml[4096], MhT[4096], MlT[4096];
    const int l = blockIdx.x, tid = threadIdx.x;
    const int w = tid >> 6, ln = tid & 63, ll = ln & 15, lh = ln >> 4;
    const float* src = A + l * 4096;
    for (int i = tid; i < 4096; i += 256) {
        float v = src[i];
        unsigned short hi = f2bf(v);
        unsigned short lo = f2bf(v - bf2f(hi));
        int r = i >> 6, c = i & 63;
        Mh[swz(r, c, 64)] = hi;  Ml[swz(r, c, 64)] = lo;
        MhT[swz(c, r, 64)] = hi; MlT[swz(c, r, 64)] = lo;
    }
    __syncthreads();
    for (int it = 0; it < 6; it++) {
        f32x4 acc[4] = {};
#pragma unroll
        for (int ks = 0; ks < 2; ks++) {
            int ar = w * 16 + ll, c0 = ks * 32 + lh * 8;
            short8 ah = *reinterpret_cast<const short8*>(&Mh[swz(ar, c0, 64)]);
            short8 al = *reinterpret_cast<const short8*>(&Ml[swz(ar, c0, 64)]);
#pragma unroll
            for (int nf = 0; nf < 4; nf++) {
                int br = nf * 16 + ll;
                short8 bh = *reinterpret_cast<const short8*>(&MhT[swz(br, c0, 64)]);
                short8 bl = *reinterpret_cast<const short8*>(&MlT[swz(br, c0, 64)]);
                acc[nf] = __builtin_amdgcn_mfma_f32_16x16x32_bf16(ah, bh, acc[nf], 0, 0, 0);
                acc[nf] = __builtin_amdgcn_mfma_f32_16x16x32_bf16(ah, bl, acc[nf], 0, 0, 0);
                acc[nf] = __builtin_amdgcn_mfma_f32_16x16x32_bf16(al, bh, acc[nf], 0, 0, 0);
            }
        }
        __syncthreads();
#pragma unroll
        for (int nf = 0; nf < 4; nf++)
#pragma unroll
            for (int r = 0; r < 4; r++) {
                float v = acc[nf][r];
                int row = w * 16 + lh * 4 + r, col = nf * 16 + ll;
                unsigned short hi = f2bf(v);
                unsigned short lo = f2bf(v - bf2f(hi));
                Mh[swz(row, col, 64)] = hi;  Ml[swz(row, col, 64)] = lo;
                MhT[swz(col, row, 64)] = hi; MlT[swz(col, row, 64)] = lo;
            }
        __syncthreads();
    }
    for (int i = tid; i < 4096; i += 256) {
        int r = i >> 6, c = i & 63;
        Apow[l * 4096 + i] = bf2f(Mh[swz(r, c, 64)]) + bf2f(Ml[swz(r, c, 64)]);
    }
}

// ---------------- fused in-proj (fp32 x direct) + LN, BM=32, full N=256 ----------------
__global__ __launch_bounds__(256) void in_ln_k(const float* __restrict__ x,
                                               const unsigned short* __restrict__ w_in,
                                               const float* __restrict__ inb,
                                               const float* __restrict__ lng, const float* __restrict__ lnb,
                                               float* __restrict__ h, unsigned short* __restrict__ xnb) {
    __shared__ float hnf[32 * 260];
    const int tid = threadIdx.x, l = tid & 63, w = tid >> 6;
    const int ll = l & 15, lh = l >> 4;
    const int mf = w >> 1, nh = w & 1;
    const int m0 = blockIdx.x * 32;
    const float* Ap = x + (size_t)(m0 + mf * 16 + ll) * DIN + lh * 8;
    const unsigned short* Wp = w_in + (size_t)(nh * 128 + ll) * DIN + lh * 8;
    f32x4 acc[8] = {};
#pragma unroll
    for (int kb = 0; kb < DIN; kb += 128) {
        float4 a0[4], a1[4];
#pragma unroll
        for (int ks = 0; ks < 4; ks++) {
            a0[ks] = *reinterpret_cast<const float4*>(Ap + kb + ks * 32);
            a1[ks] = *reinterpret_cast<const float4*>(Ap + kb + ks * 32 + 4);
        }
        short8 af[4];
#pragma unroll
        for (int ks = 0; ks < 4; ks++) {
            short8 t;
            t[0] = (short)f2bf(a0[ks].x); t[1] = (short)f2bf(a0[ks].y);
            t[2] = (short)f2bf(a0[ks].z); t[3] = (short)f2bf(a0[ks].w);
            t[4] = (short)f2bf(a1[ks].x); t[5] = (short)f2bf(a1[ks].y);
            t[6] = (short)f2bf(a1[ks].z); t[7] = (short)f2bf(a1[ks].w);
            af[ks] = t;
        }
#pragma unroll
        for (int half = 0; half < 2; half++) {
            short8 bfx[8][2];
#pragma unroll
            for (int ks = 0; ks < 2; ks++)
#pragma unroll
                for (int j = 0; j < 8; j++)
                    bfx[j][ks] = *reinterpret_cast<const short8*>(Wp + (size_t)(j * 16) * DIN + kb + (half * 2 + ks) * 32);
            SBAR();   // all 16 W-loads (and the 8 A-loads above) issued before MFMA
#pragma unroll
            for (int ks = 0; ks < 2; ks++)
#pragma unroll
                for (int j = 0; j < 8; j++)
                    acc[j] = __builtin_amdgcn_mfma_f32_16x16x32_bf16(af[half * 2 + ks], bfx[j][ks], acc[j], 0, 0, 0);
            SBAR();   // keep next half's loads from inflating register pressure
        }
    }
#pragma unroll
    for (int j = 0; j < 8; j++)
#pragma unroll
        for (int r = 0; r < 4; r++) {
            int rowl = mf * 16 + lh * 4 + r;
            int col = nh * 128 + j * 16 + ll;
            hnf[rowl * 260 + col] = acc[j][r] + inb[col];
        }
    __syncthreads();
#pragma unroll
    for (int q = 0; q < 8; q++) {
        int rowl = w * 8 + q;
        size_t gidx = (size_t)(m0 + rowl) * HD + l * 4;
        const float* vp = &hnf[rowl * 260 + l * 4];
        float o0 = vp[0], o1 = vp[1], o2 = vp[2], o3 = vp[3];
        float s = o0 + o1 + o2 + o3;
        float s2 = o0 * o0 + o1 * o1 + o2 * o2 + o3 * o3;
#pragma unroll
        for (int mm = 1; mm < 64; mm <<= 1) { s += __shfl_xor(s, mm); s2 += __shfl_xor(s2, mm); }
        float mean = s * (1.f / 256.f);
        float var = s2 * (1.f / 256.f) - mean * mean;
        float rstd = rsqrtf(var + 1e-5f);
        int c = l * 4;
        float4 ov; ov.x = o0; ov.y = o1; ov.z = o2; ov.w = o3;
        *reinterpret_cast<float4*>(h + gidx) = ov;
        ushort4 xo;
        xo.x = f2bf((o0 - mean) * rstd * lng[c + 0] + lnb[c + 0]);
        xo.y = f2bf((o1 - mean) * rstd * lng[c + 1] + lnb[c + 1]);
        xo.z = f2bf((o2 - mean) * rstd * lng[c + 2] + lnb[c + 2]);
        xo.w = f2bf((o3 - mean) * rstd * lng[c + 3] + lnb[c + 3]);
        *reinterpret_cast<ushort4*>(xnb + gidx) = xo;
    }
}

// ---------------- MFMA core with KB=128 register preload + sched fences ----------------
template <int K>
__device__ __forceinline__ void mfma_kb(const unsigned short* __restrict__ Ap,
                                        const unsigned short* __restrict__ Wp,
                                        f32x4 (*acc)[4]) {
#pragma unroll
    for (int kb = 0; kb < K; kb += 128) {
        short8 af[2][4], bf[4][4];
#pragma unroll
        for (int ks = 0; ks < 4; ks++)
#pragma unroll
            for (int mf = 0; mf < 2; mf++)
                af[mf][ks] = *reinterpret_cast<const short8*>(Ap + (size_t)mf * 16 * K + kb + ks * 32);
#pragma unroll
        for (int ks = 0; ks < 4; ks++)
#pragma unroll
            for (int nf = 0; nf < 4; nf++)
                bf[nf][ks] = *reinterpret_cast<const short8*>(Wp + (size_t)nf * 16 * K + kb + ks * 32);
        SBAR();   // all 24 loads issued before any MFMA (forbids load sinking)
#pragma unroll
        for (int ks = 0; ks < 4; ks++)
#pragma unroll
            for (int mf = 0; mf < 2; mf++)
#pragma unroll
                for (int nf = 0; nf < 4; nf++)
                    acc[mf][nf] = __builtin_amdgcn_mfma_f32_16x16x32_bf16(af[mf][ks], bf[nf][ks], acc[mf][nf], 0, 0, 0);
        SBAR();   // cap register pressure: next kb's loads stay after this point
    }
}

// ---------------- final GEMM, BM=128, fp32 out, nontemporal stores ----------------
template <int K, int N>
__global__ __launch_bounds__(256) void gemm_k(const unsigned short* __restrict__ A,
                                              const unsigned short* __restrict__ W,
                                              const float* __restrict__ bias,
                                              float* __restrict__ outf) {
    __shared__ float sf[128 * 68];
    const int tid = threadIdx.x, l = tid & 63, w = tid >> 6;
    const int ll = l & 15, lh = l >> 4;
    const int m0b = blockIdx.x * 128;
    const int m0 = m0b + w * 32;
    const int n0 = blockIdx.y * 64;
    f32x4 acc[2][4] = {};
    mfma_kb<K>(A + (size_t)(m0 + ll) * K + lh * 8, W + (size_t)(n0 + ll) * K + lh * 8, acc);
#pragma unroll
    for (int mf = 0; mf < 2; mf++)
#pragma unroll
        for (int nf = 0; nf < 4; nf++)
#pragma unroll
            for (int r = 0; r < 4; r++) {
                int rowl = w * 32 + mf * 16 + lh * 4 + r;
                int col = nf * 16 + ll;
                sf[rowl * 68 + col] = acc[mf][nf][r] + bias[n0 + col];
            }
    __syncthreads();
#pragma unroll
    for (int p = 0; p < 8; p++) {
        int rowl = p * 16 + (tid >> 4);
        int col = (tid & 15) * 4;
        f32x4 v = *reinterpret_cast<const f32x4*>(&sf[rowl * 68 + col]);
        __builtin_nontemporal_store(v, reinterpret_cast<f32x4*>(outf + (size_t)(m0b + rowl) * N + n0 + col));
    }
}

// ---------------- fused gate + ip GEMM, BM=128 (grid y: 0..3 gate, 4 = ip) ----------------
__global__ __launch_bounds__(256) void gateip_k(const unsigned short* __restrict__ xnb,
                                                const unsigned short* __restrict__ wg,
                                                const unsigned short* __restrict__ wip,
                                                const float* __restrict__ gbias, const float* __restrict__ ipb,
                                                const float* __restrict__ Bv, const float* __restrict__ bA,
                                                unsigned short* __restrict__ gB, float* __restrict__ u) {
    __shared__ char smem[128 * 68 * 4];
    float* sf = (float*)smem;
    unsigned short* su = (unsigned short*)smem;
    const int tid = threadIdx.x, l = tid & 63, w = tid >> 6;
    const int ll = l & 15, lh = l >> 4;
    const int m0b = blockIdx.x * 128;
    const int m0 = m0b + w * 32;
    const int y = blockIdx.y;
    const bool gate = (y < 4);
    const int n0 = gate ? y * 64 : 0;
    f32x4 acc[2][4] = {};
    mfma_kb<HD>(xnb + (size_t)(m0 + ll) * HD + lh * 8,
                (gate ? wg : wip) + (size_t)(n0 + ll) * HD + lh * 8, acc);
    if (gate) {
#pragma unroll
        for (int mf = 0; mf < 2; mf++)
#pragma unroll
            for (int nf = 0; nf < 4; nf++)
#pragma unroll
                for (int r = 0; r < 4; r++) {
                    int rowl = w * 32 + mf * 16 + lh * 4 + r;
                    int col = nf * 16 + ll;
                    float v = acc[mf][nf][r] + gbias[n0 + col];
                    su[rowl * 72 + col] = f2bf(1.f / (1.f + __expf(-v)));
                }
        __syncthreads();
#pragma unroll
        for (int p = 0; p < 8; p++) {
            int rowl = p * 16 + (tid >> 4);
            int col = (tid & 15) * 4;
            ushort4 v = *reinterpret_cast<const ushort4*>(&su[rowl * 72 + col]);
            *reinterpret_cast<ushort4*>(gB + (size_t)(m0b + rowl) * HD + n0 + col) = v;
        }
    } else {
#pragma unroll
        for (int mf = 0; mf < 2; mf++)
#pragma unroll
            for (int nf = 0; nf < 4; nf++)
#pragma unroll
                for (int r = 0; r < 4; r++) {
                    int rowl = w * 32 + mf * 16 + lh * 4 + r;
                    int col = nf * 16 + ll;
                    float v = acc[mf][nf][r] + ipb[col];
                    sf[rowl * 68 + col] = Bv[col] * v + bA[col];
                }
        __syncthreads();
#pragma unroll
        for (int p = 0; p < 8; p++) {
            int rowl = p * 16 + (tid >> 4);
            int col = (tid & 15) * 4;
            int m = m0b + rowl;           // bt-order
            int t = m & 2047, b2 = m >> 11;
            float4 v = *reinterpret_cast<const float4*>(&sf[rowl * 68 + col]);
            *reinterpret_cast<float4*>(u + ((size_t)((t << 3) + b2)) * 64 + col) = v;
        }
    }
}

// ---------------- fused Cm + proj + blend + LN(next layer) ----------------
template <bool LAST>
__global__ __launch_bounds__(256) void post3_k(const unsigned short* __restrict__ Hs,
                                               const unsigned short* __restrict__ wc,
                                               const float* __restrict__ bC,
                                               const unsigned short* __restrict__ wp,
                                               const float* __restrict__ pb,
                                               const unsigned short* __restrict__ gB,
                                               unsigned short* __restrict__ xnb,
                                               float* __restrict__ h, unsigned short* __restrict__ hb,
                                               const float* __restrict__ lng2, const float* __restrict__ lnb2) {
    __shared__ unsigned short ys[32 * 256];   // XOR-swizzled
    __shared__ float hnf[32 * 264];
    const int tid = threadIdx.x, l = tid & 63, w = tid >> 6;
    const int ll = l & 15, lh = l >> 4;
    const int mf = w >> 1, nh = w & 1;
    const int m0 = blockIdx.x * 32;          // tb-order
    {
        short8 ha[2], cb[8][2];
        const unsigned short* Ap = Hs + (size_t)(m0 + mf * 16 + ll) * SD + lh * 8;
#pragma unroll
        for (int ks = 0; ks < 2; ks++)
            ha[ks] = *reinterpret_cast<const short8*>(Ap + ks * 32);
#pragma unroll
        for (int ks = 0; ks < 2; ks++)
#pragma unroll
            for (int j = 0; j < 8; j++)
                cb[j][ks] = *reinterpret_cast<const short8*>(wc + (size_t)((nh * 8 + j) * 16 + ll) * SD + ks * 32 + lh * 8);
        SBAR();
        f32x4 acc[8] = {};
#pragma unroll
        for (int ks = 0; ks < 2; ks++)
#pragma unroll
            for (int j = 0; j < 8; j++)
                acc[j] = __builtin_amdgcn_mfma_f32_16x16x32_bf16(ha[ks], cb[j][ks], acc[j], 0, 0, 0);
#pragma unroll
        for (int j = 0; j < 8; j++)
#pragma unroll
            for (int r = 0; r < 4; r++) {
                int rowl = mf * 16 + lh * 4 + r;
                int col = (nh * 8 + j) * 16 + ll;
                ys[swz(rowl, col, 256)] = f2bf(acc[j][r] + bC[col]);
            }
    }
    __syncthreads();
    {
        f32x4 acc2[8] = {};
        const int arow = mf * 16 + ll;
#pragma unroll
        for (int kb = 0; kb < 2; kb++) {
            short8 pwf[8][4];
#pragma unroll
            for (int ks = 0; ks < 4; ks++)
#pragma unroll
                for (int j = 0; j < 8; j++)
                    pwf[j][ks] = *reinterpret_cast<const short8*>(wp + (size_t)((nh * 8 + j) * 16 + ll) * HD + kb * 128 + ks * 32 + lh * 8);
            SBAR();   // 32 weight loads in flight before MFMA
#pragma unroll
            for (int ks = 0; ks < 4; ks++) {
                int c0 = kb * 128 + ks * 32 + lh * 8;
                short8 a = *reinterpret_cast<const short8*>(&ys[swz(arow, c0, 256)]);
#pragma unroll
                for (int j = 0; j < 8; j++)
                    acc2[j] = __builtin_amdgcn_mfma_f32_16x16x32_bf16(a, pwf[j][ks], acc2[j], 0, 0, 0);
            }
            SBAR();   // cap pressure: kb=1 loads stay after kb=0 MFMAs
        }
#pragma unroll
        for (int j = 0; j < 8; j++)
#pragma unroll
            for (int r = 0; r < 4; r++) {
                int rowl = mf * 16 + lh * 4 + r;
                int col = (nh * 8 + j) * 16 + ll;
                hnf[rowl * 264 + col] = acc2[j][r] + pb[col];
            }
    }
    __syncthreads();
#pragma unroll
    for (int q = 0; q < 8; q++) {
        int rowl = w * 8 + q;
        int m = m0 + rowl;               // tb-order
        int t = m >> 3, b2 = m & 7;
        size_t gidx = ((size_t)((b2 << 11) + t)) * HD + l * 4;
        float4 hv = *reinterpret_cast<const float4*>(h + gidx);
        ushort4 gv = *reinterpret_cast<const ushort4*>(gB + gidx);
        ushort4 xv = *reinterpret_cast<const ushort4*>(xnb + gidx);
        const float* vp = &hnf[rowl * 264 + l * 4];
        float g0 = bf2f(gv.x), g1 = bf2f(gv.y), g2 = bf2f(gv.z), g3 = bf2f(gv.w);
        float o0 = hv.x + g0 * vp[0] + (1.f - g0) * bf2f(xv.x);
        float o1 = hv.y + g1 * vp[1] + (1.f - g1) * bf2f(xv.y);
        float o2 = hv.z + g2 * vp[2] + (1.f - g2) * bf2f(xv.z);
        float o3 = hv.w + g3 * vp[3] + (1.f - g3) * bf2f(xv.w);
        if constexpr (LAST) {
            ushort4 hbv;
            hbv.x = f2bf(o0); hbv.y = f2bf(o1); hbv.z = f2bf(o2); hbv.w = f2bf(o3);
            *reinterpret_cast<ushort4*>(hb + gidx) = hbv;
        } else {
            float s = o0 + o1 + o2 + o3;
            float s2 = o0 * o0 + o1 * o1 + o2 * o2 + o3 * o3;
#pragma unroll
            for (int mm = 1; mm < 64; mm <<= 1) { s += __shfl_xor(s, mm); s2 += __shfl_xor(s2, mm); }
            float mean = s * (1.f / 256.f);
            float var = s2 * (1.f / 256.f) - mean * mean;
            float rstd = rsqrtf(var + 1e-5f);
            int c = l * 4;
            float4 ov; ov.x = o0; ov.y = o1; ov.z = o2; ov.w = o3;
            *reinterpret_cast<float4*>(h + gidx) = ov;
            ushort4 xo;
            xo.x = f2bf((o0 - mean) * rstd * lng2[c + 0] + lnb2[c + 0]);
            xo.y = f2bf((o1 - mean) * rstd * lng2[c + 1] + lnb2[c + 1]);
            xo.z = f2bf((o2 - mean) * rstd * lng2[c + 2] + lnb2[c + 2]);
            xo.w = f2bf((o3 - mean) * rstd * lng2[c + 3] + lnb2[c + 3]);
            *reinterpret_cast<ushort4*>(xnb + gidx) = xo;
        }
    }
}

// ---------------- scan helpers ----------------
__device__ __forceinline__ void loadA64(const float* __restrict__ Af, int s, float* a) {
#pragma unroll
    for (int q = 0; q < 16; q++) {
        float4 v = reinterpret_cast<const float4*>(Af + s * 64)[q];
        a[q * 4 + 0] = v.x; a[q * 4 + 1] = v.y; a[q * 4 + 2] = v.z; a[q * 4 + 3] = v.w;
    }
}

__device__ __forceinline__ float step64(const float* a, float h, float uu) {
    float ac0 = uu, ac1 = 0.f, ac2 = 0.f, ac3 = 0.f;
#pragma unroll
    for (int k = 0; k < 64; k += 4) {
        float b0 = __int_as_float(__builtin_amdgcn_readlane(__float_as_int(h), k + 0));
        float b1 = __int_as_float(__builtin_amdgcn_readlane(__float_as_int(h), k + 1));
        float b2 = __int_as_float(__builtin_amdgcn_readlane(__float_as_int(h), k + 2));
        float b3 = __int_as_float(__builtin_amdgcn_readlane(__float_as_int(h), k + 3));
        ac0 = fmaf(b0, a[k + 0], ac0);
        ac1 = fmaf(b1, a[k + 1], ac1);
        ac2 = fmaf(b2, a[k + 2], ac2);
        ac3 = fmaf(b3, a[k + 3], ac3);
    }
    return (ac0 + ac1) + (ac2 + ac3);
}

__global__ __launch_bounds__(64) void scan_chunk_k(const float* __restrict__ Af,
                                                   const float* __restrict__ u,
                                                   float* __restrict__ Slast) {
    const int c = blockIdx.x >> 3, b = blockIdx.x & 7;
    const int s = threadIdx.x;
    float a[64];
    loadA64(Af, s, a);
    const float* up = u + (c * CLEN) * 512 + b * 64 + s;
    float uv[CLEN];
#pragma unroll
    for (int i = 0; i < CLEN; i++) uv[i] = up[i * 512];
    float h = 0.f;
#pragma unroll
    for (int i = 0; i < CLEN; i++) h = step64(a, h, uv[i]);
    Slast[blockIdx.x * 64 + s] = h;
}

__global__ __launch_bounds__(64) void carry_k(const float* __restrict__ Apow,
                                              const float* __restrict__ Slast,
                                              float* __restrict__ Carry) {
    const int b = blockIdx.x;
    const int s = threadIdx.x;
    float a[64];
    loadA64(Apow, s, a);
    float sv[NCHUNK];
#pragma unroll
    for (int c = 0; c < NCHUNK; c++) sv[c] = Slast[(c * 8 + b) * 64 + s];
    float carry = 0.f;
#pragma unroll
    for (int c = 0; c < NCHUNK; c++) {
        Carry[(c * 8 + b) * 64 + s] = carry;
        carry = step64(a, carry, sv[c]);
    }
}

__global__ __launch_bounds__(64) void replay_k(const float* __restrict__ Af,
                                               const float* __restrict__ u,
                                               const float* __restrict__ Carry,
                                               unsigned short* __restrict__ Hs,
                                               int* __restrict__ flag) {
    const int c = blockIdx.x >> 3, b = blockIdx.x & 7;
    const int s = threadIdx.x;
    float a[64];
    loadA64(Af, s, a);
    const float* up = u + (c * CLEN) * 512 + b * 64 + s;
    float uv[CLEN];
#pragma unroll
    for (int i = 0; i < CLEN; i++) uv[i] = up[i * 512];
    float h = Carry[blockIdx.x * 64 + s];
    unsigned short* hp = Hs + (c * CLEN) * 512 + b * 64 + s;
    bool bad = false;
#pragma unroll
    for (int i = 0; i < CLEN; i++) {
        h = step64(a, h, uv[i]);
        bad |= (fabsf(h) > 10.f);
        hp[i * 512] = f2bf(h);
    }
    if (__any(bad ? 1 : 0)) {
        if (s == 0) atomicOr(flag, 1);
    }
}

__global__ __launch_bounds__(64) void scan_seq_k(const float* __restrict__ Af,
                                                 const float* __restrict__ u,
                                                 unsigned short* __restrict__ Hs,
                                                 const int* __restrict__ flag) {
    if (*flag == 0) return;
    const int b = blockIdx.x;
    const int s = threadIdx.x;
    float a[64];
    loadA64(Af, s, a);
    float h = 0.f;
    for (int t = 0; t < T_LEN; t++) {
        float uu = u[((t << 3) + b) * 64 + s];
        float hp = step64(a, h, uu);
        h = fminf(fmaxf(hp, -10.f), 10.f);
        Hs[((t << 3) + b) * 64 + s] = f2bf(h);
    }
}

// ---------------- launch ----------------
extern "C" void kernel_launch(void* const* d_in, const int* in_sizes, int n_in,
                              void* d_out, int out_size, void* d_ws, size_t ws_size,
                              hipStream_t stream) {
    const float* x    = (const float*)d_in[0];
    const float* inw  = (const float*)d_in[1];
    const float* inb  = (const float*)d_in[2];
    const float* lng  = (const float*)d_in[3];
    const float* lnb  = (const float*)d_in[4];
    const float* ipw  = (const float*)d_in[5];
    const float* ipb  = (const float*)d_in[6];
    const float* Amat = (const float*)d_in[7];
    const float* Bv   = (const float*)d_in[8];
    const float* Cm   = (const float*)d_in[9];
    const float* bA   = (const float*)d_in[10];
    const float* bC   = (const float*)d_in[11];
    const float* gw   = (const float*)d_in[12];
    const float* gbia = (const float*)d_in[13];
    const float* pw   = (const float*)d_in[14];
    const float* pb   = (const float*)d_in[15];
    const float* ow   = (const float*)d_in[16];
    const float* ob   = (const float*)d_in[17];

    char* ws = (char*)d_ws;
    float*          u  = (float*)(ws + 0);                   // 4 MB
    unsigned short* Hs = (unsigned short*)(ws + 4194304);    // 2 MB
    unsigned short* hb = (unsigned short*)(ws + 14680064);   // 8 MB
    unsigned short* wb = (unsigned short*)(ws + 25165824);   // 2 MB
    float*          h  = (float*)(ws + 27262976);            // 16 MB
    unsigned short* xnb = (unsigned short*)(ws + 44040192);  // 8 MB
    unsigned short* gB  = (unsigned short*)(ws + 52428800);  // 8 MB

    char* sc = (char*)d_out;   // small scratch; fully overwritten by final GEMM
    float* Apow  = (float*)(sc + 0);          // 64 KB: [4][64][64] (A^64)
    float* Slast = (float*)(sc + 65536);      // 64 KB
    float* Carry = (float*)(sc + 131072);     // 64 KB
    int*   flag  = (int*)(sc + 196608);       // 16 B

    const unsigned short* w_in = wb + 0;
    const unsigned short* w_ip = wb + 196608;
    const unsigned short* w_g  = wb + 262144;
    const unsigned short* w_p  = wb + 524288;
    const unsigned short* w_c  = wb + 786432;
    const unsigned short* w_o  = wb + 851968;

    hipMemsetAsync(flag, 0, 16, stream);
    cvt_w_k<<<4096, 256, 0, stream>>>(inw, ipw, gw, pw, Cm, ow, wb);
    matpow_k<<<4, 256, 0, stream>>>(Amat, Apow);

    in_ln_k<<<512, 256, 0, stream>>>(x, w_in, inb, lng, lnb, h, xnb);
    for (int i = 0; i < 4; i++) {
        gateip_k<<<dim3(128, 5), 256, 0, stream>>>(xnb, w_g + i * 65536, w_ip + i * 16384,
                                                   gbia + i * HD, ipb + i * SD,
                                                   Bv + i * SD, bA + i * SD, gB, u);
        scan_chunk_k<<<256, 64, 0, stream>>>(Amat + i * 4096, u, Slast);
        carry_k<<<8, 64, 0, stream>>>(Apow + i * 4096, Slast, Carry);
        replay_k<<<256, 64, 0, stream>>>(Amat + i * 4096, u, Carry, Hs, flag + i);
        scan_seq_k<<<8, 64, 0, stream>>>(Amat + i * 4096, u, Hs, flag + i);
        if (i < 3)
            post3_k<false><<<512, 256, 0, stream>>>(Hs, w_c + i * 16384, bC + i * HD,
                                                    w_p + i * 65536, pb + i * HD, gB, xnb, h, hb,
                                                    lng + (i + 1) * HD, lnb + (i + 1) * HD);
        else
            post3_k<true><<<512, 256, 0, stream>>>(Hs, w_c + i * 16384, bC + i * HD,
                                                   w_p + i * 65536, pb + i * HD, gB, xnb, h, hb,
                                                   lng, lnb);
    }
    gemm_k<HD, DOUT><<<dim3(128, 12), 256, 0, stream>>>(hb, w_o, ob, (float*)d_out);
}

// Round 12
// 492.922 us; speedup vs baseline: 2.4901x; 1.0279x over previous
//
#include <hip/hip_runtime.h>

typedef float f32x4 __attribute__((ext_vector_type(4)));
typedef short short8 __attribute__((ext_vector_type(8)));

#define T_LEN 2048
#define HD 256
#define SD 64
#define DIN 768
#define DOUT 768
#define NCHUNK 32
#define CLEN 64

#define SBAR() __builtin_amdgcn_sched_barrier(0)

__device__ __forceinline__ unsigned short f2bf(float f) {
    unsigned int u = __float_as_uint(f);
    unsigned int r = u + 0x7FFFu + ((u >> 16) & 1u);
    return (unsigned short)(r >> 16);
}
__device__ __forceinline__ float bf2f(unsigned short h) {
    return __uint_as_float(((unsigned int)h) << 16);
}
__device__ __forceinline__ int swz(int row, int col, int stride) {
    return row * stride + (col ^ ((row & 7) << 3));
}

// ---------------- weight conversion ----------------
__global__ __launch_bounds__(256) void cvt_w_k(const float* __restrict__ s0, const float* __restrict__ s1,
                                               const float* __restrict__ s2, const float* __restrict__ s3,
                                               const float* __restrict__ s4, const float* __restrict__ s5,
                                               unsigned short* __restrict__ d) {
    int i = blockIdx.x * 256 + threadIdx.x;
    if (i >= 1048576) return;
    float v;
    if (i < 196608)      v = s0[i];
    else if (i < 262144) v = s1[i - 196608];
    else if (i < 524288) v = s2[i - 262144];
    else if (i < 786432) v = s3[i - 524288];
    else if (i < 851968) v = s4[i - 786432];
    else                 v = s5[i - 851968];
    d[i] = f2bf(v);
}

// ---------------- A^64 via bf16-split MFMA (6 squarings, verified) ----------------
__global__ __launch_bounds__(256) void matpow_k(const float* __restrict__ A, float* __restrict__ Apow) {
    __shared__ unsigned short Mh[4096], Ml[4096], MhT[4096], MlT[4096];
    const int l = blockIdx.x, tid = threadIdx.x;
    const int w = tid >> 6, ln = tid & 63, ll = ln & 15, lh = ln >> 4;
    const float* src = A + l * 4096;
    for (int i = tid; i < 4096; i += 256) {
        float v = src[i];
        unsigned short hi = f2bf(v);
        unsigned short lo = f2bf(v - bf2f(hi));
        int r = i >> 6, c = i & 63;
        Mh[swz(r, c, 64)] = hi;  Ml[swz(r, c, 64)] = lo;
        MhT[swz(c, r, 64)] = hi; MlT[swz(c, r, 64)] = lo;
    }
    __syncthreads();
    for (int it = 0; it < 6; it++) {
        f32x4 acc[4] = {};
#pragma unroll
        for (int ks = 0; ks < 2; ks++) {
            int ar = w * 16 + ll, c0 = ks * 32 + lh * 8;
            short8 ah = *reinterpret_cast<const short8*>(&Mh[swz(ar, c0, 64)]);
            short8 al = *reinterpret_cast<const short8*>(&Ml[swz(ar, c0, 64)]);
#pragma unroll
            for (int nf = 0; nf < 4; nf++) {
                int br = nf * 16 + ll;
                short8 bh = *reinterpret_cast<const short8*>(&MhT[swz(br, c0, 64)]);
                short8 bl = *reinterpret_cast<const short8*>(&MlT[swz(br, c0, 64)]);
                acc[nf] = __builtin_amdgcn_mfma_f32_16x16x32_bf16(ah, bh, acc[nf], 0, 0, 0);
                acc[nf] = __builtin_amdgcn_mfma_f32_16x16x32_bf16(ah, bl, acc[nf], 0, 0, 0);
                acc[nf] = __builtin_amdgcn_mfma_f32_16x16x32_bf16(al, bh, acc[nf], 0, 0, 0);
            }
        }
        __syncthreads();
#pragma unroll
        for (int nf = 0; nf < 4; nf++)
#pragma unroll
            for (int r = 0; r < 4; r++) {
                float v = acc[nf][r];
                int row = w * 16 + lh * 4 + r, col = nf * 16 + ll;
                unsigned short hi = f2bf(v);
                unsigned short lo = f2bf(v - bf2f(hi));
                Mh[swz(row, col, 64)] = hi;  Ml[swz(row, col, 64)] = lo;
                MhT[swz(col, row, 64)] = hi; MlT[swz(col, row, 64)] = lo;
            }
        __syncthreads();
    }
    for (int i = tid; i < 4096; i += 256) {
        int r = i >> 6, c = i & 63;
        Apow[l * 4096 + i] = bf2f(Mh[swz(r, c, 64)]) + bf2f(Ml[swz(r, c, 64)]);
    }
}

// ---------------- fused in-proj (fp32 x direct) + LN, BM=32, full N=256 ----------------
__global__ __launch_bounds__(256) void in_ln_k(const float* __restrict__ x,
                                               const unsigned short* __restrict__ w_in,
                                               const float* __restrict__ inb,
                                               const float* __restrict__ lng, const float* __restrict__ lnb,
                                               float* __restrict__ h, unsigned short* __restrict__ xnb) {
    __shared__ float hnf[32 * 260];
    const int tid = threadIdx.x, l = tid & 63, w = tid >> 6;
    const int ll = l & 15, lh = l >> 4;
    const int mf = w >> 1, nh = w & 1;
    const int m0 = blockIdx.x * 32;
    const float* Ap = x + (size_t)(m0 + mf * 16 + ll) * DIN + lh * 8;
    const unsigned short* Wp = w_in + (size_t)(nh * 128 + ll) * DIN + lh * 8;
    f32x4 acc[8] = {};
#pragma unroll
    for (int kb = 0; kb < DIN; kb += 128) {
        float4 a0[4], a1[4];
#pragma unroll
        for (int ks = 0; ks < 4; ks++) {
            a0[ks] = *reinterpret_cast<const float4*>(Ap + kb + ks * 32);
            a1[ks] = *reinterpret_cast<const float4*>(Ap + kb + ks * 32 + 4);
        }
        short8 af[4];
#pragma unroll
        for (int ks = 0; ks < 4; ks++) {
            short8 t;
            t[0] = (short)f2bf(a0[ks].x); t[1] = (short)f2bf(a0[ks].y);
            t[2] = (short)f2bf(a0[ks].z); t[3] = (short)f2bf(a0[ks].w);
            t[4] = (short)f2bf(a1[ks].x); t[5] = (short)f2bf(a1[ks].y);
            t[6] = (short)f2bf(a1[ks].z); t[7] = (short)f2bf(a1[ks].w);
            af[ks] = t;
        }
#pragma unroll
        for (int half = 0; half < 2; half++) {
            short8 bfx[8][2];
#pragma unroll
            for (int ks = 0; ks < 2; ks++)
#pragma unroll
                for (int j = 0; j < 8; j++)
                    bfx[j][ks] = *reinterpret_cast<const short8*>(Wp + (size_t)(j * 16) * DIN + kb + (half * 2 + ks) * 32);
            SBAR();   // loads grouped before MFMA; NEXT group may overlap these MFMAs
#pragma unroll
            for (int ks = 0; ks < 2; ks++)
#pragma unroll
                for (int j = 0; j < 8; j++)
                    acc[j] = __builtin_amdgcn_mfma_f32_16x16x32_bf16(af[half * 2 + ks], bfx[j][ks], acc[j], 0, 0, 0);
        }
    }
#pragma unroll
    for (int j = 0; j < 8; j++)
#pragma unroll
        for (int r = 0; r < 4; r++) {
            int rowl = mf * 16 + lh * 4 + r;
            int col = nh * 128 + j * 16 + ll;
            hnf[rowl * 260 + col] = acc[j][r] + inb[col];
        }
    __syncthreads();
#pragma unroll
    for (int q = 0; q < 8; q++) {
        int rowl = w * 8 + q;
        size_t gidx = (size_t)(m0 + rowl) * HD + l * 4;
        const float* vp = &hnf[rowl * 260 + l * 4];
        float o0 = vp[0], o1 = vp[1], o2 = vp[2], o3 = vp[3];
        float s = o0 + o1 + o2 + o3;
        float s2 = o0 * o0 + o1 * o1 + o2 * o2 + o3 * o3;
#pragma unroll
        for (int mm = 1; mm < 64; mm <<= 1) { s += __shfl_xor(s, mm); s2 += __shfl_xor(s2, mm); }
        float mean = s * (1.f / 256.f);
        float var = s2 * (1.f / 256.f) - mean * mean;
        float rstd = rsqrtf(var + 1e-5f);
        int c = l * 4;
        float4 ov; ov.x = o0; ov.y = o1; ov.z = o2; ov.w = o3;
        *reinterpret_cast<float4*>(h + gidx) = ov;
        ushort4 xo;
        xo.x = f2bf((o0 - mean) * rstd * lng[c + 0] + lnb[c + 0]);
        xo.y = f2bf((o1 - mean) * rstd * lng[c + 1] + lnb[c + 1]);
        xo.z = f2bf((o2 - mean) * rstd * lng[c + 2] + lnb[c + 2]);
        xo.w = f2bf((o3 - mean) * rstd * lng[c + 3] + lnb[c + 3]);
        *reinterpret_cast<ushort4*>(xnb + gidx) = xo;
    }
}

// ---------------- MFMA core with KB=128 register preload; pipeline across kb ----------------
template <int K>
__device__ __forceinline__ void mfma_kb(const unsigned short* __restrict__ Ap,
                                        const unsigned short* __restrict__ Wp,
                                        f32x4 (*acc)[4]) {
#pragma unroll
    for (int kb = 0; kb < K; kb += 128) {
        short8 af[2][4], bf[4][4];
#pragma unroll
        for (int ks = 0; ks < 4; ks++)
#pragma unroll
            for (int mf = 0; mf < 2; mf++)
                af[mf][ks] = *reinterpret_cast<const short8*>(Ap + (size_t)mf * 16 * K + kb + ks * 32);
#pragma unroll
        for (int ks = 0; ks < 4; ks++)
#pragma unroll
            for (int nf = 0; nf < 4; nf++)
                bf[nf][ks] = *reinterpret_cast<const short8*>(Wp + (size_t)nf * 16 * K + kb + ks * 32);
        SBAR();   // all 24 loads issued before this iter's MFMAs; next iter's loads may overlap
#pragma unroll
        for (int ks = 0; ks < 4; ks++)
#pragma unroll
            for (int mf = 0; mf < 2; mf++)
#pragma unroll
                for (int nf = 0; nf < 4; nf++)
                    acc[mf][nf] = __builtin_amdgcn_mfma_f32_16x16x32_bf16(af[mf][ks], bf[nf][ks], acc[mf][nf], 0, 0, 0);
    }
}

// ---------------- final GEMM, BM=128, fp32 out, nontemporal stores ----------------
template <int K, int N>
__global__ __launch_bounds__(256) void gemm_k(const unsigned short* __restrict__ A,
                                              const unsigned short* __restrict__ W,
                                              const float* __restrict__ bias,
                                              float* __restrict__ outf) {
    __shared__ float sf[128 * 68];
    const int tid = threadIdx.x, l = tid & 63, w = tid >> 6;
    const int ll = l & 15, lh = l >> 4;
    const int m0b = blockIdx.x * 128;
    const int m0 = m0b + w * 32;
    const int n0 = blockIdx.y * 64;
    f32x4 acc[2][4] = {};
    mfma_kb<K>(A + (size_t)(m0 + ll) * K + lh * 8, W + (size_t)(n0 + ll) * K + lh * 8, acc);
#pragma unroll
    for (int mf = 0; mf < 2; mf++)
#pragma unroll
        for (int nf = 0; nf < 4; nf++)
#pragma unroll
            for (int r = 0; r < 4; r++) {
                int rowl = w * 32 + mf * 16 + lh * 4 + r;
                int col = nf * 16 + ll;
                sf[rowl * 68 + col] = acc[mf][nf][r] + bias[n0 + col];
            }
    __syncthreads();
#pragma unroll
    for (int p = 0; p < 8; p++) {
        int rowl = p * 16 + (tid >> 4);
        int col = (tid & 15) * 4;
        f32x4 v = *reinterpret_cast<const f32x4*>(&sf[rowl * 68 + col]);
        __builtin_nontemporal_store(v, reinterpret_cast<f32x4*>(outf + (size_t)(m0b + rowl) * N + n0 + col));
    }
}

// ---------------- fused gate + ip GEMM, BM=128 (grid y: 0..3 gate, 4 = ip) ----------------
__global__ __launch_bounds__(256) void gateip_k(const unsigned short* __restrict__ xnb,
                                                const unsigned short* __restrict__ wg,
                                                const unsigned short* __restrict__ wip,
                                                const float* __restrict__ gbias, const float* __restrict__ ipb,
                                                const float* __restrict__ Bv, const float* __restrict__ bA,
                                                unsigned short* __restrict__ gB, float* __restrict__ u) {
    __shared__ char smem[128 * 68 * 4];
    float* sf = (float*)smem;
    unsigned short* su = (unsigned short*)smem;
    const int tid = threadIdx.x, l = tid & 63, w = tid >> 6;
    const int ll = l & 15, lh = l >> 4;
    const int m0b = blockIdx.x * 128;
    const int m0 = m0b + w * 32;
    const int y = blockIdx.y;
    const bool gate = (y < 4);
    const int n0 = gate ? y * 64 : 0;
    f32x4 acc[2][4] = {};
    mfma_kb<HD>(xnb + (size_t)(m0 + ll) * HD + lh * 8,
                (gate ? wg : wip) + (size_t)(n0 + ll) * HD + lh * 8, acc);
    if (gate) {
#pragma unroll
        for (int mf = 0; mf < 2; mf++)
#pragma unroll
            for (int nf = 0; nf < 4; nf++)
#pragma unroll
                for (int r = 0; r < 4; r++) {
                    int rowl = w * 32 + mf * 16 + lh * 4 + r;
                    int col = nf * 16 + ll;
                    float v = acc[mf][nf][r] + gbias[n0 + col];
                    su[rowl * 72 + col] = f2bf(1.f / (1.f + __expf(-v)));
                }
        __syncthreads();
#pragma unroll
        for (int p = 0; p < 8; p++) {
            int rowl = p * 16 + (tid >> 4);
            int col = (tid & 15) * 4;
            ushort4 v = *reinterpret_cast<const ushort4*>(&su[rowl * 72 + col]);
            *reinterpret_cast<ushort4*>(gB + (size_t)(m0b + rowl) * HD + n0 + col) = v;
        }
    } else {
#pragma unroll
        for (int mf = 0; mf < 2; mf++)
#pragma unroll
            for (int nf = 0; nf < 4; nf++)
#pragma unroll
                for (int r = 0; r < 4; r++) {
                    int rowl = w * 32 + mf * 16 + lh * 4 + r;
                    int col = nf * 16 + ll;
                    float v = acc[mf][nf][r] + ipb[col];
                    sf[rowl * 68 + col] = Bv[col] * v + bA[col];
                }
        __syncthreads();
#pragma unroll
        for (int p = 0; p < 8; p++) {
            int rowl = p * 16 + (tid >> 4);
            int col = (tid & 15) * 4;
            int m = m0b + rowl;           // bt-order
            int t = m & 2047, b2 = m >> 11;
            float4 v = *reinterpret_cast<const float4*>(&sf[rowl * 68 + col]);
            *reinterpret_cast<float4*>(u + ((size_t)((t << 3) + b2)) * 64 + col) = v;
        }
    }
}

// ---------------- fused Cm + proj + blend + LN(next layer) ----------------
template <bool LAST>
__global__ __launch_bounds__(256) void post3_k(const unsigned short* __restrict__ Hs,
                                               const unsigned short* __restrict__ wc,
                                               const float* __restrict__ bC,
                                               const unsigned short* __restrict__ wp,
                                               const float* __restrict__ pb,
                                               const unsigned short* __restrict__ gB,
                                               unsigned short* __restrict__ xnb,
                                               float* __restrict__ h, unsigned short* __restrict__ hb,
                                               const float* __restrict__ lng2, const float* __restrict__ lnb2) {
    __shared__ unsigned short ys[32 * 256];   // XOR-swizzled
    __shared__ float hnf[32 * 264];
    const int tid = threadIdx.x, l = tid & 63, w = tid >> 6;
    const int ll = l & 15, lh = l >> 4;
    const int mf = w >> 1, nh = w & 1;
    const int m0 = blockIdx.x * 32;          // tb-order
    {
        short8 ha[2], cb[8][2];
        const unsigned short* Ap = Hs + (size_t)(m0 + mf * 16 + ll) * SD + lh * 8;
#pragma unroll
        for (int ks = 0; ks < 2; ks++)
            ha[ks] = *reinterpret_cast<const short8*>(Ap + ks * 32);
#pragma unroll
        for (int ks = 0; ks < 2; ks++)
#pragma unroll
            for (int j = 0; j < 8; j++)
                cb[j][ks] = *reinterpret_cast<const short8*>(wc + (size_t)((nh * 8 + j) * 16 + ll) * SD + ks * 32 + lh * 8);
        SBAR();
        f32x4 acc[8] = {};
#pragma unroll
        for (int ks = 0; ks < 2; ks++)
#pragma unroll
            for (int j = 0; j < 8; j++)
                acc[j] = __builtin_amdgcn_mfma_f32_16x16x32_bf16(ha[ks], cb[j][ks], acc[j], 0, 0, 0);
#pragma unroll
        for (int j = 0; j < 8; j++)
#pragma unroll
            for (int r = 0; r < 4; r++) {
                int rowl = mf * 16 + lh * 4 + r;
                int col = (nh * 8 + j) * 16 + ll;
                ys[swz(rowl, col, 256)] = f2bf(acc[j][r] + bC[col]);
            }
    }
    __syncthreads();
    {
        f32x4 acc2[8] = {};
        const int arow = mf * 16 + ll;
#pragma unroll
        for (int kb = 0; kb < 2; kb++) {
            short8 pwf[8][4];
#pragma unroll
            for (int ks = 0; ks < 4; ks++)
#pragma unroll
                for (int j = 0; j < 8; j++)
                    pwf[j][ks] = *reinterpret_cast<const short8*>(wp + (size_t)((nh * 8 + j) * 16 + ll) * HD + kb * 128 + ks * 32 + lh * 8);
            SBAR();   // 32 weight loads in flight before MFMA; kb=1 loads may overlap kb=0 MFMAs
#pragma unroll
            for (int ks = 0; ks < 4; ks++) {
                int c0 = kb * 128 + ks * 32 + lh * 8;
                short8 a = *reinterpret_cast<const short8*>(&ys[swz(arow, c0, 256)]);
#pragma unroll
                for (int j = 0; j < 8; j++)
                    acc2[j] = __builtin_amdgcn_mfma_f32_16x16x32_bf16(a, pwf[j][ks], acc2[j], 0, 0, 0);
            }
        }
#pragma unroll
        for (int j = 0; j < 8; j++)
#pragma unroll
            for (int r = 0; r < 4; r++) {
                int rowl = mf * 16 + lh * 4 + r;
                int col = (nh * 8 + j) * 16 + ll;
                hnf[rowl * 264 + col] = acc2[j][r] + pb[col];
            }
    }
    __syncthreads();
#pragma unroll
    for (int q = 0; q < 8; q++) {
        int rowl = w * 8 + q;
        int m = m0 + rowl;               // tb-order
        int t = m >> 3, b2 = m & 7;
        size_t gidx = ((size_t)((b2 << 11) + t)) * HD + l * 4;
        float4 hv = *reinterpret_cast<const float4*>(h + gidx);
        ushort4 gv = *reinterpret_cast<const ushort4*>(gB + gidx);
        ushort4 xv = *reinterpret_cast<const ushort4*>(xnb + gidx);
        const float* vp = &hnf[rowl * 264 + l * 4];
        float g0 = bf2f(gv.x), g1 = bf2f(gv.y), g2 = bf2f(gv.z), g3 = bf2f(gv.w);
        float o0 = hv.x + g0 * vp[0] + (1.f - g0) * bf2f(xv.x);
        float o1 = hv.y + g1 * vp[1] + (1.f - g1) * bf2f(xv.y);
        float o2 = hv.z + g2 * vp[2] + (1.f - g2) * bf2f(xv.z);
        float o3 = hv.w + g3 * vp[3] + (1.f - g3) * bf2f(xv.w);
        if constexpr (LAST) {
            ushort4 hbv;
            hbv.x = f2bf(o0); hbv.y = f2bf(o1); hbv.z = f2bf(o2); hbv.w = f2bf(o3);
            *reinterpret_cast<ushort4*>(hb + gidx) = hbv;
        } else {
            float s = o0 + o1 + o2 + o3;
            float s2 = o0 * o0 + o1 * o1 + o2 * o2 + o3 * o3;
#pragma unroll
            for (int mm = 1; mm < 64; mm <<= 1) { s += __shfl_xor(s, mm); s2 += __shfl_xor(s2, mm); }
            float mean = s * (1.f / 256.f);
            float var = s2 * (1.f / 256.f) - mean * mean;
            float rstd = rsqrtf(var + 1e-5f);
            int c = l * 4;
            float4 ov; ov.x = o0; ov.y = o1; ov.z = o2; ov.w = o3;
            *reinterpret_cast<float4*>(h + gidx) = ov;
            ushort4 xo;
            xo.x = f2bf((o0 - mean) * rstd * lng2[c + 0] + lnb2[c + 0]);
            xo.y = f2bf((o1 - mean) * rstd * lng2[c + 1] + lnb2[c + 1]);
            xo.z = f2bf((o2 - mean) * rstd * lng2[c + 2] + lnb2[c + 2]);
            xo.w = f2bf((o3 - mean) * rstd * lng2[c + 3] + lnb2[c + 3]);
            *reinterpret_cast<ushort4*>(xnb + gidx) = xo;
        }
    }
}

// ---------------- scan helpers ----------------
__device__ __forceinline__ void loadA64(const float* __restrict__ Af, int s, float* a) {
#pragma unroll
    for (int q = 0; q < 16; q++) {
        float4 v = reinterpret_cast<const float4*>(Af + s * 64)[q];
        a[q * 4 + 0] = v.x; a[q * 4 + 1] = v.y; a[q * 4 + 2] = v.z; a[q * 4 + 3] = v.w;
    }
}

__device__ __forceinline__ float step64(const float* a, float h, float uu) {
    float ac0 = uu, ac1 = 0.f, ac2 = 0.f, ac3 = 0.f;
#pragma unroll
    for (int k = 0; k < 64; k += 4) {
        float b0 = __int_as_float(__builtin_amdgcn_readlane(__float_as_int(h), k + 0));
        float b1 = __int_as_float(__builtin_amdgcn_readlane(__float_as_int(h), k + 1));
        float b2 = __int_as_float(__builtin_amdgcn_readlane(__float_as_int(h), k + 2));
        float b3 = __int_as_float(__builtin_amdgcn_readlane(__float_as_int(h), k + 3));
        ac0 = fmaf(b0, a[k + 0], ac0);
        ac1 = fmaf(b1, a[k + 1], ac1);
        ac2 = fmaf(b2, a[k + 2], ac2);
        ac3 = fmaf(b3, a[k + 3], ac3);
    }
    return (ac0 + ac1) + (ac2 + ac3);
}

__global__ __launch_bounds__(64) void scan_chunk_k(const float* __restrict__ Af,
                                                   const float* __restrict__ u,
                                                   float* __restrict__ Slast) {
    const int c = blockIdx.x >> 3, b = blockIdx.x & 7;
    const int s = threadIdx.x;
    float a[64];
    loadA64(Af, s, a);
    const float* up = u + (c * CLEN) * 512 + b * 64 + s;
    float uv[CLEN];
#pragma unroll
    for (int i = 0; i < CLEN; i++) uv[i] = up[i * 512];
    float h = 0.f;
#pragma unroll
    for (int i = 0; i < CLEN; i++) h = step64(a, h, uv[i]);
    Slast[blockIdx.x * 64 + s] = h;
}

// replay with in-block carry recomputation (carry_k fused away)
__global__ __launch_bounds__(64) void replay_k(const float* __restrict__ Af,
                                               const float* __restrict__ Apow,
                                               const float* __restrict__ u,
                                               const float* __restrict__ Slast,
                                               unsigned short* __restrict__ Hs,
                                               int* __restrict__ flag) {
    const int c = blockIdx.x >> 3, b = blockIdx.x & 7;
    const int s = threadIdx.x;
    // phase A: recompute carry for this chunk: carry = sum_{j<c} A64^(c-1-j) @ Slast[j]
    float a[64];
    float carry = 0.f;
    if (c > 0) {
        loadA64(Apow, s, a);
        for (int j = 0; j < c; j++) {
            float sl = Slast[(j * 8 + b) * 64 + s];
            carry = step64(a, carry, sl);
        }
    }
    // phase B: replay chunk from carry
    loadA64(Af, s, a);
    const float* up = u + (c * CLEN) * 512 + b * 64 + s;
    float uv[CLEN];
#pragma unroll
    for (int i = 0; i < CLEN; i++) uv[i] = up[i * 512];
    float h = carry;
    unsigned short* hp = Hs + (c * CLEN) * 512 + b * 64 + s;
    bool bad = false;
#pragma unroll
    for (int i = 0; i < CLEN; i++) {
        h = step64(a, h, uv[i]);
        bad |= (fabsf(h) > 10.f);
        hp[i * 512] = f2bf(h);
    }
    if (__any(bad ? 1 : 0)) {
        if (s == 0) atomicOr(flag, 1);
    }
}

__global__ __launch_bounds__(64) void scan_seq_k(const float* __restrict__ Af,
                                                 const float* __restrict__ u,
                                                 unsigned short* __restrict__ Hs,
                                                 const int* __restrict__ flag) {
    if (*flag == 0) return;
    const int b = blockIdx.x;
    const int s = threadIdx.x;
    float a[64];
    loadA64(Af, s, a);
    float h = 0.f;
    for (int t = 0; t < T_LEN; t++) {
        float uu = u[((t << 3) + b) * 64 + s];
        float hp = step64(a, h, uu);
        h = fminf(fmaxf(hp, -10.f), 10.f);
        Hs[((t << 3) + b) * 64 + s] = f2bf(h);
    }
}

// ---------------- launch ----------------
extern "C" void kernel_launch(void* const* d_in, const int* in_sizes, int n_in,
                              void* d_out, int out_size, void* d_ws, size_t ws_size,
                              hipStream_t stream) {
    const float* x    = (const float*)d_in[0];
    const float* inw  = (const float*)d_in[1];
    const float* inb  = (const float*)d_in[2];
    const float* lng  = (const float*)d_in[3];
    const float* lnb  = (const float*)d_in[4];
    const float* ipw  = (const float*)d_in[5];
    const float* ipb  = (const float*)d_in[6];
    const float* Amat = (const float*)d_in[7];
    const float* Bv   = (const float*)d_in[8];
    const float* Cm   = (const float*)d_in[9];
    const float* bA   = (const float*)d_in[10];
    const float* bC   = (const float*)d_in[11];
    const float* gw   = (const float*)d_in[12];
    const float* gbia = (const float*)d_in[13];
    const float* pw   = (const float*)d_in[14];
    const float* pb   = (const float*)d_in[15];
    const float* ow   = (const float*)d_in[16];
    const float* ob   = (const float*)d_in[17];

    char* ws = (char*)d_ws;
    float*          u  = (float*)(ws + 0);                   // 4 MB
    unsigned short* Hs = (unsigned short*)(ws + 4194304);    // 2 MB
    unsigned short* hb = (unsigned short*)(ws + 14680064);   // 8 MB
    unsigned short* wb = (unsigned short*)(ws + 25165824);   // 2 MB
    float*          h  = (float*)(ws + 27262976);            // 16 MB
    unsigned short* xnb = (unsigned short*)(ws + 44040192);  // 8 MB
    unsigned short* gB  = (unsigned short*)(ws + 52428800);  // 8 MB

    char* sc = (char*)d_out;   // small scratch; fully overwritten by final GEMM
    float* Apow  = (float*)(sc + 0);          // 64 KB: [4][64][64] (A^64)
    float* Slast = (float*)(sc + 65536);      // 64 KB
    int*   flag  = (int*)(sc + 196608);       // 16 B

    const unsigned short* w_in = wb + 0;
    const unsigned short* w_ip = wb + 196608;
    const unsigned short* w_g  = wb + 262144;
    const unsigned short* w_p  = wb + 524288;
    const unsigned short* w_c  = wb + 786432;
    const unsigned short* w_o  = wb + 851968;

    hipMemsetAsync(flag, 0, 16, stream);
    cvt_w_k<<<4096, 256, 0, stream>>>(inw, ipw, gw, pw, Cm, ow, wb);
    matpow_k<<<4, 256, 0, stream>>>(Amat, Apow);

    in_ln_k<<<512, 256, 0, stream>>>(x, w_in, inb, lng, lnb, h, xnb);
    for (int i = 0; i < 4; i++) {
        gateip_k<<<dim3(128, 5), 256, 0, stream>>>(xnb, w_g + i * 65536, w_ip + i * 16384,
                                                   gbia + i * HD, ipb + i * SD,
                                                   Bv + i * SD, bA + i * SD, gB, u);
        scan_chunk_k<<<256, 64, 0, stream>>>(Amat + i * 4096, u, Slast);
        replay_k<<<256, 64, 0, stream>>>(Amat + i * 4096, Apow + i * 4096, u, Slast, Hs, flag + i);
        scan_seq_k<<<8, 64, 0, stream>>>(Amat + i * 4096, u, Hs, flag + i);
        if (i < 3)
            post3_k<false><<<512, 256, 0, stream>>>(Hs, w_c + i * 16384, bC + i * HD,
                                                    w_p + i * 65536, pb + i * HD, gB, xnb, h, hb,
                                                    lng + (i + 1) * HD, lnb + (i + 1) * HD);
        else
            post3_k<true><<<512, 256, 0, stream>>>(Hs, w_c + i * 16384, bC + i * HD,
                                                   w_p + i * 65536, pb + i * HD, gB, xnb, h, hb,
                                                   lng, lnb);
    }
    gemm_k<HD, DOUT><<<dim3(128, 12), 256, 0, stream>>>(hb, w_o, ob, (float*)d_out);
}